// Round 16
// baseline (1963.933 us; speedup 1.0000x reference)
//
#include <hip/hip_runtime.h>
#include <math.h>

#define RR 512
#define BB 16
#define TT 64
#define KC 2
#define NN 256
#define NBLK 256

__device__ __forceinline__ float sigmoidf_(float x) {
    return 1.0f / (1.0f + __expf(-x));
}
__device__ __forceinline__ float wave_sum(float v) {
    #pragma unroll
    for (int off = 32; off > 0; off >>= 1) v += __shfl_xor(v, off, 64);
    return v;
}
__device__ __forceinline__ float wave_max(float v) {
    #pragma unroll
    for (int off = 32; off > 0; off >>= 1) v = fmaxf(v, __shfl_xor(v, off, 64));
    return v;
}

// ---- relaxed agent-scope atomic ops (MALL-coherent, no cache fences) ----
__device__ __forceinline__ float ldA(const float* p) {
    return __hip_atomic_load(p, __ATOMIC_RELAXED, __HIP_MEMORY_SCOPE_AGENT);
}
__device__ __forceinline__ void stA(float* p, float v) {
    __hip_atomic_store(p, v, __ATOMIC_RELAXED, __HIP_MEMORY_SCOPE_AGENT);
}
__device__ __forceinline__ unsigned ldU(const unsigned* p) {
    return __hip_atomic_load(p, __ATOMIC_RELAXED, __HIP_MEMORY_SCOPE_AGENT);
}
__device__ __forceinline__ void stU(unsigned* p, unsigned v) {
    __hip_atomic_store(p, v, __ATOMIC_RELAXED, __HIP_MEMORY_SCOPE_AGENT);
}
__device__ __forceinline__ float2 ldA2(const float* p) {
    unsigned long long v = __hip_atomic_load((const unsigned long long*)p,
                                             __ATOMIC_RELAXED, __HIP_MEMORY_SCOPE_AGENT);
    float2 r;
    r.x = __uint_as_float((unsigned)v);
    r.y = __uint_as_float((unsigned)(v >> 32));
    return r;
}
__device__ __forceinline__ void stA2(float* p, float x, float y) {
    unsigned long long v = ((unsigned long long)__float_as_uint(y) << 32)
                         | (unsigned long long)__float_as_uint(x);
    __hip_atomic_store((unsigned long long*)p, v, __ATOMIC_RELAXED,
                       __HIP_MEMORY_SCOPE_AGENT);
}

// ---- coherent dwordx4 batches, waitcnt INSIDE each asm (r14-proven: no
// issue->wait live-range window). sc0 sc1 -> MALL-coherent, no cache fences.
// Flat 64-bit vaddr only (r15 lesson: "s" pointer constraints may land in
// VGPRs -> invalid saddr operand).

// 8 loads, 8 flat addresses (proven r14) — staging + stage D.
#define LDG8(d0,d1,d2,d3,d4,d5,d6,d7, q0,q1,q2,q3,q4,q5,q6,q7)      \
    asm volatile(                                                     \
        "global_load_dwordx4 %0, %8, off sc0 sc1\n\t"                \
        "global_load_dwordx4 %1, %9, off sc0 sc1\n\t"                \
        "global_load_dwordx4 %2, %10, off sc0 sc1\n\t"               \
        "global_load_dwordx4 %3, %11, off sc0 sc1\n\t"               \
        "global_load_dwordx4 %4, %12, off sc0 sc1\n\t"               \
        "global_load_dwordx4 %5, %13, off sc0 sc1\n\t"               \
        "global_load_dwordx4 %6, %14, off sc0 sc1\n\t"               \
        "global_load_dwordx4 %7, %15, off sc0 sc1\n\t"               \
        "s_waitcnt vmcnt(0)"                                          \
        : "=&v"(d0), "=&v"(d1), "=&v"(d2), "=&v"(d3),                 \
          "=&v"(d4), "=&v"(d5), "=&v"(d6), "=&v"(d7)                  \
        : "v"(q0), "v"(q1), "v"(q2), "v"(q3),                         \
          "v"(q4), "v"(q5), "v"(q6), "v"(q7)                          \
        : "memory")

// 16 loads from 4 flat addresses x offset:{0,1024,2048,3072}; ONE wait.
// (stage C: mbuf rows are 2048B apart, row halves at +1024B)
#define LDG16O(d0,d1,d2,d3,d4,d5,d6,d7,d8,d9,d10,d11,d12,d13,d14,d15,\
               q0,q1,q2,q3)                                           \
    asm volatile(                                                     \
        "global_load_dwordx4 %0, %16, off sc0 sc1\n\t"               \
        "global_load_dwordx4 %1, %16, off offset:1024 sc0 sc1\n\t"   \
        "global_load_dwordx4 %2, %16, off offset:2048 sc0 sc1\n\t"   \
        "global_load_dwordx4 %3, %16, off offset:3072 sc0 sc1\n\t"   \
        "global_load_dwordx4 %4, %17, off sc0 sc1\n\t"               \
        "global_load_dwordx4 %5, %17, off offset:1024 sc0 sc1\n\t"   \
        "global_load_dwordx4 %6, %17, off offset:2048 sc0 sc1\n\t"   \
        "global_load_dwordx4 %7, %17, off offset:3072 sc0 sc1\n\t"   \
        "global_load_dwordx4 %8, %18, off sc0 sc1\n\t"               \
        "global_load_dwordx4 %9, %18, off offset:1024 sc0 sc1\n\t"   \
        "global_load_dwordx4 %10, %18, off offset:2048 sc0 sc1\n\t"  \
        "global_load_dwordx4 %11, %18, off offset:3072 sc0 sc1\n\t"  \
        "global_load_dwordx4 %12, %19, off sc0 sc1\n\t"              \
        "global_load_dwordx4 %13, %19, off offset:1024 sc0 sc1\n\t"  \
        "global_load_dwordx4 %14, %19, off offset:2048 sc0 sc1\n\t"  \
        "global_load_dwordx4 %15, %19, off offset:3072 sc0 sc1\n\t"  \
        "s_waitcnt vmcnt(0)"                                          \
        : "=&v"(d0), "=&v"(d1), "=&v"(d2), "=&v"(d3),                 \
          "=&v"(d4), "=&v"(d5), "=&v"(d6), "=&v"(d7),                 \
          "=&v"(d8), "=&v"(d9), "=&v"(d10), "=&v"(d11),               \
          "=&v"(d12), "=&v"(d13), "=&v"(d14), "=&v"(d15)              \
        : "v"(q0), "v"(q1), "v"(q2), "v"(q3)                          \
        : "memory")

struct f8 { float4 a, b; };
// split-slice mapping: lane's 8 floats of a 512-row = [lane*4,+4) and
// [256+lane*4,+4). Conflict-free LDS b128. Used for LDS-resident operands.
__device__ __forceinline__ f8 ld8s(const float* row, int lane) {
    f8 r;
    r.a = *(const float4*)(row + lane * 4);
    r.b = *(const float4*)(row + 256 + lane * 4);
    return r;
}
__device__ __forceinline__ void st8s(float* row, const f8& v, int lane) {
    *(float4*)(row + lane * 4) = v.a;
    *(float4*)(row + 256 + lane * 4) = v.b;
}
__device__ __forceinline__ f8 ld8sA2(const float* row, int lane) {
    float2 t0 = ldA2(row + lane * 4);
    float2 t1 = ldA2(row + lane * 4 + 2);
    float2 t2 = ldA2(row + 256 + lane * 4);
    float2 t3 = ldA2(row + 256 + lane * 4 + 2);
    f8 r;
    r.a = make_float4(t0.x, t0.y, t1.x, t1.y);
    r.b = make_float4(t2.x, t2.y, t3.x, t3.y);
    return r;
}
__device__ __forceinline__ float dot8(const f8& x, const f8& y) {
    return x.a.x*y.a.x + x.a.y*y.a.y + x.a.z*y.a.z + x.a.w*y.a.w
         + x.b.x*y.b.x + x.b.y*y.b.y + x.b.z*y.b.z + x.b.w*y.b.w;
}
// inline function, NOT a macro (macro param `w` collides with float4::w)
__device__ __forceinline__ void upd8(f8& m, const f8& u, float zf) {
    m.a.x = zf * (m.a.x + u.a.x); m.a.y = zf * (m.a.y + u.a.y);
    m.a.z = zf * (m.a.z + u.a.z); m.a.w = zf * (m.a.w + u.a.w);
    m.b.x = zf * (m.b.x + u.b.x); m.b.y = zf * (m.b.y + u.b.y);
    m.b.z = zf * (m.b.z + u.b.z); m.b.w = zf * (m.b.w + u.b.w);
}
__device__ __forceinline__ void fmaacc8(f8& acc, float sc, const f8& m, float wgt) {
    acc.a.x = acc.a.x*sc + wgt*m.a.x; acc.a.y = acc.a.y*sc + wgt*m.a.y;
    acc.a.z = acc.a.z*sc + wgt*m.a.z; acc.a.w = acc.a.w*sc + wgt*m.a.w;
    acc.b.x = acc.b.x*sc + wgt*m.b.x; acc.b.y = acc.b.y*sc + wgt*m.b.y;
    acc.b.z = acc.b.z*sc + wgt*m.b.z; acc.b.w = acc.b.w*sc + wgt*m.b.w;
}

// Payload-halving butterfly: p[0..15] per-b partials across 64 lanes ->
// each lane returns the full sum for b = (lane>>2)&15.
__device__ __forceinline__ float reduce16(float* p, int lane) {
    float q[8];
    {
        bool hi = (lane & 32) != 0;
        #pragma unroll
        for (int i = 0; i < 8; ++i) {
            float snd = hi ? p[i] : p[i + 8];
            float r = __shfl_xor(snd, 32, 64);
            q[i] = (hi ? p[i + 8] : p[i]) + r;
        }
    }
    float s4[4];
    {
        bool hi = (lane & 16) != 0;
        #pragma unroll
        for (int i = 0; i < 4; ++i) {
            float snd = hi ? q[i] : q[i + 4];
            float r = __shfl_xor(snd, 16, 64);
            s4[i] = (hi ? q[i + 4] : q[i]) + r;
        }
    }
    float d2[2];
    {
        bool hi = (lane & 8) != 0;
        #pragma unroll
        for (int i = 0; i < 2; ++i) {
            float snd = hi ? s4[i] : s4[i + 2];
            float r = __shfl_xor(snd, 8, 64);
            d2[i] = (hi ? s4[i + 2] : s4[i]) + r;
        }
    }
    float v;
    {
        bool hi = (lane & 4) != 0;
        float snd = hi ? d2[0] : d2[1];
        float r = __shfl_xor(snd, 4, 64);
        v = (hi ? d2[1] : d2[0]) + r;
    }
    v += __shfl_xor(v, 2, 64);
    v += __shfl_xor(v, 1, 64);
    return v;
}

__device__ __forceinline__ float gatedotR(const f8* A, const f8& w, int lane) {
    float p[16];
    #pragma unroll
    for (int b = 0; b < 16; ++b) p[b] = dot8(A[b], w);
    return reduce16(p, lane);
}
// gatedot streaming rows from LDS (low register pressure, block-local)
__device__ __forceinline__ float gatedotL(const float* act, const f8& w, int lane) {
    float p[16];
    #pragma unroll
    for (int b = 0; b < 16; ++b) {
        f8 r = ld8s(act + b * 512, lane);
        p[b] = dot8(r, w);
    }
    return reduce16(p, lane);
}
__device__ __forceinline__ void ldacts(f8* A, const float* act, int lane) {
    #pragma unroll
    for (int b = 0; b < 16; ++b) A[b] = ld8s(act + b * 512, lane);
}

// ---- store-slot barrier (RMW-free, fence-free). slots[256] hold each
// block's monotonically increasing generation. Arrival = per-wave vmcnt
// drain -> syncthreads -> one relaxed store. Wait = wave-0 lanes poll until
// __all(slot >= tgt). No release hop, no counter reset, no ABA (monotone).
__device__ __forceinline__ void barArrive(unsigned* slots, int sidx, unsigned tgt) {
    asm volatile("s_waitcnt vmcnt(0)" ::: "memory");
    __syncthreads();
    if (threadIdx.x == 0) stU(slots + sidx, tgt);
}
__device__ __forceinline__ void gridWait(unsigned* slots, unsigned tgt) {
    if (threadIdx.x < 64) {
        const unsigned* base = slots + threadIdx.x * 4;
        for (;;) {
            bool ok = (ldU(base + 0) >= tgt) & (ldU(base + 1) >= tgt)
                    & (ldU(base + 2) >= tgt) & (ldU(base + 3) >= tgt);
            if (__all(ok)) break;
            __builtin_amdgcn_s_sleep(1);
        }
    }
    __syncthreads();
}
__device__ __forceinline__ void groupWait(unsigned* slots, int gbase, unsigned tgt) {
    if (threadIdx.x < 64) {
        const unsigned* ps = slots + gbase + (threadIdx.x & 7);
        for (;;) {
            bool ok = ldU(ps) >= tgt;
            if (__all(ok)) break;
            __builtin_amdgcn_s_sleep(1);
        }
    }
    __syncthreads();
}

// ---------------------------------------------------------------------------
// k_pre: pre[t*16+b][j] = [emb|io] @ Wih_r^T + bih_r + bhh_r   (proven r1-r14)
// ---------------------------------------------------------------------------
__global__ void k_pre(const float* __restrict__ emb, const float* __restrict__ io,
                      const float* __restrict__ Wih, const float* __restrict__ bih,
                      const float* __restrict__ bhh, float* __restrict__ pre)
{
    __shared__ float As[16][65];
    __shared__ float Bs[16][65];
    int tid = threadIdx.x;
    int row0 = blockIdx.y * 64;
    int col0 = blockIdx.x * 64;
    int ty = tid >> 4, tx = tid & 15;
    float acc[4][4] = {};
    int lr = tid >> 2;
    int lk4 = (tid & 3) * 4;
    for (int k0 = 0; k0 < 1024; k0 += 16) {
        int grow = row0 + lr;
        int b = grow & 15;
        #pragma unroll
        for (int q = 0; q < 4; ++q) {
            int k = k0 + lk4 + q;
            float v = (k < RR) ? emb[(size_t)grow * RR + k]
                               : io[(size_t)b * RR + (k - RR)];
            As[lk4 + q][lr] = v;
        }
        #pragma unroll
        for (int q = 0; q < 4; ++q) {
            int k = k0 + lk4 + q;
            Bs[lk4 + q][lr] = Wih[(size_t)(col0 + lr) * 1024 + k];
        }
        __syncthreads();
        #pragma unroll
        for (int kk = 0; kk < 16; ++kk) {
            float a[4], bbv[4];
            #pragma unroll
            for (int i = 0; i < 4; ++i) a[i] = As[kk][ty * 4 + i];
            #pragma unroll
            for (int j = 0; j < 4; ++j) bbv[j] = Bs[kk][tx * 4 + j];
            #pragma unroll
            for (int i = 0; i < 4; ++i)
                #pragma unroll
                for (int j = 0; j < 4; ++j)
                    acc[i][j] += a[i] * bbv[j];
        }
        __syncthreads();
    }
    #pragma unroll
    for (int i = 0; i < 4; ++i) {
        int grow = row0 + ty * 4 + i;
        #pragma unroll
        for (int j = 0; j < 4; ++j) {
            int gcol = col0 + tx * 4 + j;
            pre[(size_t)grow * 2048 + gcol] = acc[i][j] + bih[gcol] + bhh[gcol];
        }
    }
}

struct P {
    const float *pre, *Whh_r, *Wc, *bc, *Wih_w, *Whh_w, *bih_w, *bhh_w;
    const float *hr0, *cr0, *hw0, *cw0, *M0;
    float *mbuf, *comppre, *mpart, *mxpart, *sumpart;
    float *hrb0, *hrb1, *crS, *hwb0, *hwb1, *cwS;
    float *outputs, *Mw;
    unsigned *slots;
};

// ---------------------------------------------------------------------------
// Persistent kernel: 64-step recurrence. M + staged activations in LDS;
// weights + cr/cw in registers; store-slot barriers; bulk cross-block reads
// via single-wait coherent dwordx4 batches; stores via relaxed atomics.
// ---------------------------------------------------------------------------
__global__ void __launch_bounds__(256, 1) k_persist(P p)
{
    const int tid = threadIdx.x;
    const int bid = blockIdx.x;
    const int wv = tid >> 6;
    const int lane = tid & 63;
    const int u0 = bid * 2;
    const int kb = (bid & 7) * 4 + (bid >> 6);   // (k,b) group
    const int w2 = (bid >> 3) & 7;               // slot within group
    const int bM = kb & 15;
    const int rowG = kb * 256 + w2 * 32;
    const int sidx = kb * 8 + w2;                // barrier slot (group-contig)
    const int gbase = kb * 8;

    __shared__ float Mlds[32][512];       // 64 KB
    __shared__ float actH[16 * 512];      // 32 KB: hr_t staged; E overlay in D
    __shared__ float actW[16 * 512];      // 32 KB: hw_{t-1} staged
    __shared__ float smacc[4][512];       // 8 KB
    __shared__ float smx4[4], ssh4[4];
    __shared__ float simL[32];
    __shared__ float gsm[2][4][16];
    __shared__ float cc[2][2][16];
    __shared__ float wmx[16][2], wsm[16][2];
    __shared__ float bcsh[2];

    unsigned tg = 0;
    float mxK = 0.f, sumInvK = 0.f;
    float crR = 0.f, cwR = 0.f;

    // ---- register-resident weight slices (split-slice mapping)
    const int jA = wv * 512 + u0;
    const f8 wR0 = ld8s(p.Whh_r + (size_t)jA * 512, lane);
    const f8 wR1 = ld8s(p.Whh_r + (size_t)(jA + 1) * 512, lane);
    const f8 wW0 = ld8s(p.Whh_w + (size_t)jA * 512, lane);
    const f8 wW1 = ld8s(p.Whh_w + (size_t)(jA + 1) * 512, lane);
    const f8 wI0 = ld8s(p.Wih_w + (size_t)jA * 512, lane);
    const f8 wI1 = ld8s(p.Wih_w + (size_t)(jA + 1) * 512, lane);
    const float bw0 = p.bih_w[jA] + p.bhh_w[jA];
    const float bw1 = p.bih_w[jA + 1] + p.bhh_w[jA + 1];
    const int jj = wv >> 1, part = wv & 1;
    const int jC = u0 + jj;
    f8 wC0, wC1 = {};
    if (part == 0) {
        wC0 = ld8s(p.Wc + (size_t)jC * 1536, lane);
        wC1 = ld8s(p.Wc + (size_t)jC * 1536 + 512, lane);
    } else {
        wC0 = ld8s(p.Wc + (size_t)jC * 1536 + 1024, lane);
    }
    if (tid < 2) bcsh[tid] = p.bc[u0 + tid];
    if (tid < 32) cwR = p.cw0[(tid & 15) * 512 + u0 + (tid >> 4)];

    // ---- load this block's M rows: global M0 -> LDS (once)
    {
        const float4* src = (const float4*)(p.M0 + (size_t)rowG * 512);
        float4* dst = (float4*)&Mlds[0][0];
        #pragma unroll 4
        for (int idx = tid; idx < 32 * 128; idx += 256)
            dst[idx] = src[idx];
    }

    // ---- prologue: read-LSTM step 0 -> hr_0 (hrb0), cr_0 (register)
    {
        f8 A[16]; ldacts(A, p.hr0, lane);
        float gv0 = gatedotR(A, wR0, lane);
        float gv1 = gatedotR(A, wR1, lane);
        if ((lane & 3) == 0) {
            int b = (lane >> 2) & 15;
            gsm[0][wv][b] = gv0 + p.pre[(size_t)b * 2048 + jA];
            gsm[1][wv][b] = gv1 + p.pre[(size_t)b * 2048 + jA + 1];
        }
        __syncthreads();
        if (tid < 32) {
            int b = tid & 15, uu = tid >> 4;
            int u = u0 + uu;
            float gi = sigmoidf_(gsm[uu][0][b]);
            float gf = sigmoidf_(gsm[uu][1][b]);
            float gg = tanhf(gsm[uu][2][b]);
            float go = sigmoidf_(gsm[uu][3][b]);
            float c = gf * p.cr0[b * 512 + u] + gi * gg;
            crR = c;
            stA(p.hrb0 + b * 512 + u, go * tanhf(c));
        }
        ++tg; barArrive(p.slots, sidx, tg); gridWait(p.slots, tg);
    }

    for (int t = 0; t < TT; ++t) {
        const float* hrcur  = (t & 1) ? p.hrb1 : p.hrb0;
        float*       hrnext = (t & 1) ? p.hrb0 : p.hrb1;
        const float* hwprev = (t == 0) ? p.hw0 : (((t - 1) & 1) ? p.hwb1 : p.hwb0);
        float*       hwnext = (t & 1) ? p.hwb1 : p.hwb0;

        // ---- stage hr_t and hw_{t-1} into LDS: coherent dwordx4 batches
        {
            float4 ha[8], wa[8];
            const float* hsrc = hrcur + tid * 4;
            const float* wsrc = hwprev + tid * 4;
            LDG8(ha[0], ha[1], ha[2], ha[3], ha[4], ha[5], ha[6], ha[7],
                 hsrc, hsrc + 1024, hsrc + 2048, hsrc + 3072,
                 hsrc + 4096, hsrc + 5120, hsrc + 6144, hsrc + 7168);
            LDG8(wa[0], wa[1], wa[2], wa[3], wa[4], wa[5], wa[6], wa[7],
                 wsrc, wsrc + 1024, wsrc + 2048, wsrc + 3072,
                 wsrc + 4096, wsrc + 5120, wsrc + 6144, wsrc + 7168);
            #pragma unroll
            for (int q = 0; q < 8; ++q) {
                ((float4*)actH)[q * 256 + tid] = ha[q];
                ((float4*)actW)[q * 256 + tid] = wa[q];
            }
        }
        __syncthreads();

        // ========= stage A: deferred M update (local z) + sim + online partials
        {
            f8 h = ld8s(actH + bM * 512, lane);
            f8 w8 = {};
            if (t > 0) w8 = ld8s(actW + bM * 512, lane);
            float mx = -3.0e38f, ssum = 0.f;
            f8 macc = {};
            #pragma unroll
            for (int ii = 0; ii < 8; ++ii) {
                int rl = wv * 8 + ii;
                float4* mp0 = (float4*)&Mlds[rl][lane * 4];
                float4* mp1 = (float4*)&Mlds[rl][256 + lane * 4];
                f8 m; m.a = *mp0; m.b = *mp1;
                if (t > 0) {
                    float zf = 1.0f - __expf(simL[rl] - mxK) * sumInvK;
                    upd8(m, w8, zf);
                    *mp0 = m.a; *mp1 = m.b;
                }
                float s = wave_sum(dot8(m, h));
                float nmx = fmaxf(mx, s);
                float sc = __expf(mx - nmx);
                float wgt = __expf(s - nmx);
                fmaacc8(macc, sc, m, wgt);
                ssum = ssum * sc + wgt;
                mx = nmx;
                if (lane == 0) simL[rl] = s;
            }
            if (lane == 0) { smx4[wv] = mx; ssh4[wv] = ssum; }
            __syncthreads();
            float MXb = fmaxf(fmaxf(smx4[0], smx4[1]), fmaxf(smx4[2], smx4[3]));
            float sc2 = __expf(mx - MXb);
            float* d0 = &smacc[wv][lane * 4];
            float* d1 = &smacc[wv][256 + lane * 4];
            d0[0] = macc.a.x * sc2; d0[1] = macc.a.y * sc2;
            d0[2] = macc.a.z * sc2; d0[3] = macc.a.w * sc2;
            d1[0] = macc.b.x * sc2; d1[1] = macc.b.y * sc2;
            d1[2] = macc.b.z * sc2; d1[3] = macc.b.w * sc2;
            __syncthreads();
            {
                int r2 = tid * 2;       // 256 threads x 2 floats = 512
                float s0 = smacc[0][r2] + smacc[1][r2] + smacc[2][r2] + smacc[3][r2];
                float s1 = smacc[0][r2 + 1] + smacc[1][r2 + 1]
                         + smacc[2][r2 + 1] + smacc[3][r2 + 1];
                stA2(&p.mpart[(size_t)(kb * 8 + w2) * 512 + r2], s0, s1);
            }
            if (tid == 0) {
                float sB = ssh4[0] * __expf(smx4[0] - MXb)
                         + ssh4[1] * __expf(smx4[1] - MXb)
                         + ssh4[2] * __expf(smx4[2] - MXb)
                         + ssh4[3] * __expf(smx4[3] - MXb);
                stA(&p.mxpart[kb * 8 + w2], MXb);
                stA(&p.sumpart[kb * 8 + w2], sB);
            }
        }
        // ========= stage A2: read-LSTM gates for t+1 (LDS activations)
        if (t < 63) {
            float gv0 = gatedotL(actH, wR0, lane);
            float gv1 = gatedotL(actH, wR1, lane);
            if ((lane & 3) == 0) {
                int b = (lane >> 2) & 15;
                gsm[0][wv][b] = gv0 + p.pre[(size_t)((t + 1) * 16 + b) * 2048 + jA];
                gsm[1][wv][b] = gv1 + p.pre[(size_t)((t + 1) * 16 + b) * 2048 + jA + 1];
            }
            __syncthreads();
            if (tid < 32) {
                int b = tid & 15, uu = tid >> 4;
                int u = u0 + uu;
                float gi = sigmoidf_(gsm[uu][0][b]);
                float gf = sigmoidf_(gsm[uu][1][b]);
                float gg = tanhf(gsm[uu][2][b]);
                float go = sigmoidf_(gsm[uu][3][b]);
                float c = gf * crR + gi * gg;
                crR = c;
                stA(hrnext + b * 512 + u, go * tanhf(c));
            }
        }

        // ========= stage B-lite: group (k,b) softmax stats + mbuf slice
        ++tg; barArrive(p.slots, sidx, tg); groupWait(p.slots, gbase, tg);
        {
            float mxp[8];
            #pragma unroll
            for (int w3 = 0; w3 < 8; ++w3) mxp[w3] = ldA(&p.mxpart[kb * 8 + w3]);
            float MX = -3.0e38f;
            #pragma unroll
            for (int w3 = 0; w3 < 8; ++w3) MX = fmaxf(MX, mxp[w3]);
            float SUM = 0.f;
            #pragma unroll
            for (int w3 = 0; w3 < 8; ++w3)
                SUM += ldA(&p.sumpart[kb * 8 + w3]) * __expf(mxp[w3] - MX);
            mxK = MX;
            sumInvK = 1.0f / SUM;
            if (tid < 32) {
                int r2 = w2 * 64 + tid * 2;
                float a0 = 0.f, a1 = 0.f;
                #pragma unroll
                for (int w3 = 0; w3 < 8; ++w3) {
                    float cf = __expf(mxp[w3] - MX);
                    float2 v2 = ldA2(&p.mpart[(size_t)(kb * 8 + w3) * 512 + r2]);
                    a0 += cf * v2.x;
                    a1 += cf * v2.y;
                }
                stA2(&p.mbuf[(size_t)kb * 512 + r2], a0 * sumInvK, a1 * sumInvK);
            }
        }
        ++tg; barArrive(p.slots, sidx, tg); gridWait(p.slots, tg);

        // ========= stage C: comppre GEMV + hoisted vh = hw_prev . Whh_w
        float vh0, vh1;
        {
            vh0 = gatedotL(actW, wW0, lane);
            vh1 = gatedotL(actW, wW1, lane);
        }
        {
            float v;
            f8 Am[16];
            const float* msbase = p.mbuf + (part ? 16 * 512 : 0) + lane * 4;
            // rows are 2048B apart; halves +1024B: 4 loads per address.
            LDG16O(Am[0].a, Am[0].b, Am[1].a, Am[1].b,
                   Am[2].a, Am[2].b, Am[3].a, Am[3].b,
                   Am[4].a, Am[4].b, Am[5].a, Am[5].b,
                   Am[6].a, Am[6].b, Am[7].a, Am[7].b,
                   msbase, msbase + 1024, msbase + 2048, msbase + 3072);
            LDG16O(Am[8].a, Am[8].b, Am[9].a, Am[9].b,
                   Am[10].a, Am[10].b, Am[11].a, Am[11].b,
                   Am[12].a, Am[12].b, Am[13].a, Am[13].b,
                   Am[14].a, Am[14].b, Am[15].a, Am[15].b,
                   msbase + 4096, msbase + 5120, msbase + 6144, msbase + 7168);
            if (part == 0) {
                v = gatedotL(actH, wC0, lane) + gatedotR(Am, wC1, lane);
            } else {
                v = gatedotR(Am, wC0, lane);
            }
            if ((lane & 3) == 0) {
                int b = (lane >> 2) & 15;
                cc[jj][part][b] = v;
            }
            __syncthreads();
            if (tid < 32) {
                int b = tid & 15, jj2 = tid >> 4;
                stA(&p.comppre[b * 512 + (u0 + jj2)],
                    cc[jj2][0][b] + cc[jj2][1][b] + bcsh[jj2]);
            }
        }
        ++tg; barArrive(p.slots, sidx, tg); gridWait(p.slots, tg);

        // ========= stage D: cooperative softmax -> E (coalesced, conflict-
        // free) in actH overlay; write-LSTM gates from LDS E
        {
            float4 v4[8];
            const float* cs = p.comppre + tid * 4;
            LDG8(v4[0], v4[1], v4[2], v4[3], v4[4], v4[5], v4[6], v4[7],
                 cs, cs + 1024, cs + 2048, cs + 3072,
                 cs + 4096, cs + 5120, cs + 6144, cs + 7168);
            const int bpar = wv >> 1;     // tid>>7
            #pragma unroll
            for (int k = 0; k < 8; ++k) {
                float mk = fmaxf(fmaxf(v4[k].x, v4[k].y), fmaxf(v4[k].z, v4[k].w));
                mk = wave_max(mk);
                if (lane == 0) wmx[2 * k + bpar][wv & 1] = mk;
            }
            __syncthreads();                 // actH (hr) reads all done
            float4* Eld4 = (float4*)actH;
            #pragma unroll
            for (int k = 0; k < 8; ++k) {
                float mxb = fmaxf(wmx[2 * k + bpar][0], wmx[2 * k + bpar][1]);
                float e0 = __expf(v4[k].x - mxb), e1 = __expf(v4[k].y - mxb);
                float e2 = __expf(v4[k].z - mxb), e3 = __expf(v4[k].w - mxb);
                Eld4[k * 256 + tid] = make_float4(e0, e1, e2, e3);
                float sv = wave_sum(e0 + e1 + e2 + e3);
                if (lane == 0) wsm[2 * k + bpar][wv & 1] = sv;
            }
            __syncthreads();
            float ti0 = gatedotL(actH, wI0, lane);
            float ti1 = gatedotL(actH, wI1, lane);
            if ((lane & 3) == 0) {
                int bb = (lane >> 2) & 15;
                float siv = 1.0f / (wsm[bb][0] + wsm[bb][1]);
                gsm[0][wv][bb] = ti0 * siv + vh0 + bw0;
                gsm[1][wv][bb] = ti1 * siv + vh1 + bw1;
            }
            __syncthreads();
            if (tid < 32) {
                int bb = tid & 15, uu = tid >> 4;
                int u = u0 + uu;
                float gi = sigmoidf_(gsm[uu][0][bb]);
                float gf = sigmoidf_(gsm[uu][1][bb]);
                float gg = tanhf(gsm[uu][2][bb]);
                float go = sigmoidf_(gsm[uu][3][bb]);
                float c = gf * cwR + gi * gg;
                cwR = c;
                float h = go * tanhf(c);
                stA(hwnext + bb * 512 + u, h);
                p.outputs[(size_t)t * 8192 + bb * 512 + u] = h;
            }
        }
        ++tg; barArrive(p.slots, sidx, tg); gridWait(p.slots, tg);
    }

    // ---- epilogue: final deferred M update with (z_63, hw_63 = hwb1);
    //      write LDS M -> Mf; flush cr/cw registers to d_out
    {
        f8 w8 = ld8sA2(p.hwb1 + (size_t)bM * 512, lane);
        #pragma unroll
        for (int ii = 0; ii < 8; ++ii) {
            int rl = wv * 8 + ii;
            float zf = 1.0f - __expf(simL[rl] - mxK) * sumInvK;
            f8 m;
            m.a = *(float4*)&Mlds[rl][lane * 4];
            m.b = *(float4*)&Mlds[rl][256 + lane * 4];
            upd8(m, w8, zf);
            st8s(p.Mw + (size_t)(rowG + rl) * 512, m, lane);
        }
        if (tid < 32) {
            int b = tid & 15, uu = tid >> 4;
            int u = u0 + uu;
            p.crS[b * 512 + u] = crR;
            p.cwS[b * 512 + u] = cwR;
        }
    }
}

extern "C" void kernel_launch(void* const* d_in, const int* in_sizes, int n_in,
                              void* d_out, int out_size, void* d_ws, size_t ws_size,
                              hipStream_t stream) {
    const float* emb   = (const float*)d_in[0];
    const float* hr0   = (const float*)d_in[1];
    const float* cr0   = (const float*)d_in[2];
    const float* hw0   = (const float*)d_in[3];
    const float* cw0   = (const float*)d_in[4];
    const float* io    = (const float*)d_in[5];
    const float* M0    = (const float*)d_in[6];
    const float* Wih_r = (const float*)d_in[7];
    const float* bih_r = (const float*)d_in[9];
    const float* bhh_r = (const float*)d_in[10];

    float* out = (float*)d_out;
    float* outputs = out;                    // [64][16][512]
    float* hrS1 = out + 524288;              // hr slot = hr parity-1 buf
    float* crS  = out + 532480;
    float* hwS1 = out + 540672;              // hw slot = hw parity-1 buf
    float* cwS  = out + 548864;
    float* Mw   = out + 557056;              // Mf (written once at epilogue)

    float* ws = (float*)d_ws;
    float* pre     = ws;                     // 1024*2048
    float* mbuf    = ws + 2097152;           // 32*512
    float* comppre = mbuf + 16384;           // 16*512
    float* hrB0    = comppre + 8192;         // hr parity 0
    float* hwB0    = hrB0 + 8192;            // hw parity 0
    float* mpart   = hwB0 + 8192;            // 256*512
    float* mxpart  = mpart + 131072;         // 256
    float* sumpart = mxpart + 256;           // 256
    unsigned* slots = (unsigned*)(sumpart + 256); // 256 uints

    (void)hipMemsetAsync(slots, 0, 256 * sizeof(unsigned), stream);

    k_pre<<<dim3(32, 16), 256, 0, stream>>>(emb, io, Wih_r, bih_r, bhh_r, pre);

    P p;
    p.pre = pre;
    p.Whh_r = (const float*)d_in[8];
    p.Wc    = (const float*)d_in[11];
    p.bc    = (const float*)d_in[12];
    p.Wih_w = (const float*)d_in[13];
    p.Whh_w = (const float*)d_in[14];
    p.bih_w = (const float*)d_in[15];
    p.bhh_w = (const float*)d_in[16];
    p.hr0 = hr0; p.cr0 = cr0; p.hw0 = hw0; p.cw0 = cw0; p.M0 = M0;
    p.mbuf = mbuf; p.comppre = comppre;
    p.mpart = mpart; p.mxpart = mxpart; p.sumpart = sumpart;
    p.hrb0 = hrB0; p.hrb1 = hrS1; p.crS = crS;
    p.hwb0 = hwB0; p.hwb1 = hwS1; p.cwS = cwS;
    p.outputs = outputs; p.Mw = Mw;
    p.slots = slots;

    k_persist<<<NBLK, 256, 0, stream>>>(p);
}

// Round 17
// 1646.351 us; speedup vs baseline: 1.1929x; 1.1929x over previous
//
#include <hip/hip_runtime.h>
#include <math.h>

#define RR 512
#define BB 16
#define TT 64
#define KC 2
#define NN 256
#define NBLK 256

__device__ __forceinline__ float sigmoidf_(float x) {
    return 1.0f / (1.0f + __expf(-x));
}
__device__ __forceinline__ float wave_sum(float v) {
    #pragma unroll
    for (int off = 32; off > 0; off >>= 1) v += __shfl_xor(v, off, 64);
    return v;
}
__device__ __forceinline__ float wave_max(float v) {
    #pragma unroll
    for (int off = 32; off > 0; off >>= 1) v = fmaxf(v, __shfl_xor(v, off, 64));
    return v;
}

// ---- relaxed agent-scope atomic ops (MALL-coherent, no cache fences) ----
__device__ __forceinline__ float ldA(const float* p) {
    return __hip_atomic_load(p, __ATOMIC_RELAXED, __HIP_MEMORY_SCOPE_AGENT);
}
__device__ __forceinline__ void stA(float* p, float v) {
    __hip_atomic_store(p, v, __ATOMIC_RELAXED, __HIP_MEMORY_SCOPE_AGENT);
}
__device__ __forceinline__ unsigned ldU(const unsigned* p) {
    return __hip_atomic_load(p, __ATOMIC_RELAXED, __HIP_MEMORY_SCOPE_AGENT);
}
__device__ __forceinline__ void stU(unsigned* p, unsigned v) {
    __hip_atomic_store(p, v, __ATOMIC_RELAXED, __HIP_MEMORY_SCOPE_AGENT);
}
__device__ __forceinline__ float2 ldA2(const float* p) {
    unsigned long long v = __hip_atomic_load((const unsigned long long*)p,
                                             __ATOMIC_RELAXED, __HIP_MEMORY_SCOPE_AGENT);
    float2 r;
    r.x = __uint_as_float((unsigned)v);
    r.y = __uint_as_float((unsigned)(v >> 32));
    return r;
}
__device__ __forceinline__ void stA2(float* p, float x, float y) {
    unsigned long long v = ((unsigned long long)__float_as_uint(y) << 32)
                         | (unsigned long long)__float_as_uint(x);
    __hip_atomic_store((unsigned long long*)p, v, __ATOMIC_RELAXED,
                       __HIP_MEMORY_SCOPE_AGENT);
}

// ---- coherent dwordx4 batches, waitcnt INSIDE each asm (r14-proven: no
// issue->wait live-range window). sc0 sc1 -> MALL-coherent, no cache fences.
// Flat 64-bit vaddr only (r15 lesson: "s" constraints may land in VGPRs).
#define LDG8(d0,d1,d2,d3,d4,d5,d6,d7, q0,q1,q2,q3,q4,q5,q6,q7)      \
    asm volatile(                                                     \
        "global_load_dwordx4 %0, %8, off sc0 sc1\n\t"                \
        "global_load_dwordx4 %1, %9, off sc0 sc1\n\t"                \
        "global_load_dwordx4 %2, %10, off sc0 sc1\n\t"               \
        "global_load_dwordx4 %3, %11, off sc0 sc1\n\t"               \
        "global_load_dwordx4 %4, %12, off sc0 sc1\n\t"               \
        "global_load_dwordx4 %5, %13, off sc0 sc1\n\t"               \
        "global_load_dwordx4 %6, %14, off sc0 sc1\n\t"               \
        "global_load_dwordx4 %7, %15, off sc0 sc1\n\t"               \
        "s_waitcnt vmcnt(0)"                                          \
        : "=&v"(d0), "=&v"(d1), "=&v"(d2), "=&v"(d3),                 \
          "=&v"(d4), "=&v"(d5), "=&v"(d6), "=&v"(d7)                  \
        : "v"(q0), "v"(q1), "v"(q2), "v"(q3),                         \
          "v"(q4), "v"(q5), "v"(q6), "v"(q7)                          \
        : "memory")

#define LDG4(d0,d1,d2,d3, q0,q1,q2,q3)                                \
    asm volatile(                                                     \
        "global_load_dwordx4 %0, %4, off sc0 sc1\n\t"                \
        "global_load_dwordx4 %1, %5, off sc0 sc1\n\t"                \
        "global_load_dwordx4 %2, %6, off sc0 sc1\n\t"                \
        "global_load_dwordx4 %3, %7, off sc0 sc1\n\t"                \
        "s_waitcnt vmcnt(0)"                                          \
        : "=&v"(d0), "=&v"(d1), "=&v"(d2), "=&v"(d3)                  \
        : "v"(q0), "v"(q1), "v"(q2), "v"(q3)                          \
        : "memory")

// 16 loads from 4 flat addresses x offset:{0,1024,2048,3072}; ONE wait.
#define LDG16O(d0,d1,d2,d3,d4,d5,d6,d7,d8,d9,d10,d11,d12,d13,d14,d15,\
               q0,q1,q2,q3)                                           \
    asm volatile(                                                     \
        "global_load_dwordx4 %0, %16, off sc0 sc1\n\t"               \
        "global_load_dwordx4 %1, %16, off offset:1024 sc0 sc1\n\t"   \
        "global_load_dwordx4 %2, %16, off offset:2048 sc0 sc1\n\t"   \
        "global_load_dwordx4 %3, %16, off offset:3072 sc0 sc1\n\t"   \
        "global_load_dwordx4 %4, %17, off sc0 sc1\n\t"               \
        "global_load_dwordx4 %5, %17, off offset:1024 sc0 sc1\n\t"   \
        "global_load_dwordx4 %6, %17, off offset:2048 sc0 sc1\n\t"   \
        "global_load_dwordx4 %7, %17, off offset:3072 sc0 sc1\n\t"   \
        "global_load_dwordx4 %8, %18, off sc0 sc1\n\t"               \
        "global_load_dwordx4 %9, %18, off offset:1024 sc0 sc1\n\t"   \
        "global_load_dwordx4 %10, %18, off offset:2048 sc0 sc1\n\t"  \
        "global_load_dwordx4 %11, %18, off offset:3072 sc0 sc1\n\t"  \
        "global_load_dwordx4 %12, %19, off sc0 sc1\n\t"              \
        "global_load_dwordx4 %13, %19, off offset:1024 sc0 sc1\n\t"  \
        "global_load_dwordx4 %14, %19, off offset:2048 sc0 sc1\n\t"  \
        "global_load_dwordx4 %15, %19, off offset:3072 sc0 sc1\n\t"  \
        "s_waitcnt vmcnt(0)"                                          \
        : "=&v"(d0), "=&v"(d1), "=&v"(d2), "=&v"(d3),                 \
          "=&v"(d4), "=&v"(d5), "=&v"(d6), "=&v"(d7),                 \
          "=&v"(d8), "=&v"(d9), "=&v"(d10), "=&v"(d11),               \
          "=&v"(d12), "=&v"(d13), "=&v"(d14), "=&v"(d15)              \
        : "v"(q0), "v"(q1), "v"(q2), "v"(q3)                          \
        : "memory")

struct f8 { float4 a, b; };
// split-slice mapping: lane's 8 floats of a 512-row = [lane*4,+4) and
// [256+lane*4,+4). Conflict-free LDS b128.
__device__ __forceinline__ f8 ld8s(const float* row, int lane) {
    f8 r;
    r.a = *(const float4*)(row + lane * 4);
    r.b = *(const float4*)(row + 256 + lane * 4);
    return r;
}
__device__ __forceinline__ void st8s(float* row, const f8& v, int lane) {
    *(float4*)(row + lane * 4) = v.a;
    *(float4*)(row + 256 + lane * 4) = v.b;
}
__device__ __forceinline__ f8 ld8sA2(const float* row, int lane) {
    float2 t0 = ldA2(row + lane * 4);
    float2 t1 = ldA2(row + lane * 4 + 2);
    float2 t2 = ldA2(row + 256 + lane * 4);
    float2 t3 = ldA2(row + 256 + lane * 4 + 2);
    f8 r;
    r.a = make_float4(t0.x, t0.y, t1.x, t1.y);
    r.b = make_float4(t2.x, t2.y, t3.x, t3.y);
    return r;
}
__device__ __forceinline__ float dot8(const f8& x, const f8& y) {
    return x.a.x*y.a.x + x.a.y*y.a.y + x.a.z*y.a.z + x.a.w*y.a.w
         + x.b.x*y.b.x + x.b.y*y.b.y + x.b.z*y.b.z + x.b.w*y.b.w;
}
// inline function, NOT a macro (macro param `w` collides with float4::w)
__device__ __forceinline__ void upd8(f8& m, const f8& u, float zf) {
    m.a.x = zf * (m.a.x + u.a.x); m.a.y = zf * (m.a.y + u.a.y);
    m.a.z = zf * (m.a.z + u.a.z); m.a.w = zf * (m.a.w + u.a.w);
    m.b.x = zf * (m.b.x + u.b.x); m.b.y = zf * (m.b.y + u.b.y);
    m.b.z = zf * (m.b.z + u.b.z); m.b.w = zf * (m.b.w + u.b.w);
}
__device__ __forceinline__ void fmaacc8(f8& acc, float sc, const f8& m, float wgt) {
    acc.a.x = acc.a.x*sc + wgt*m.a.x; acc.a.y = acc.a.y*sc + wgt*m.a.y;
    acc.a.z = acc.a.z*sc + wgt*m.a.z; acc.a.w = acc.a.w*sc + wgt*m.a.w;
    acc.b.x = acc.b.x*sc + wgt*m.b.x; acc.b.y = acc.b.y*sc + wgt*m.b.y;
    acc.b.z = acc.b.z*sc + wgt*m.b.z; acc.b.w = acc.b.w*sc + wgt*m.b.w;
}

// Payload-halving butterfly: p[0..15] per-b partials across 64 lanes ->
// each lane returns the full sum for b = (lane>>2)&15.
__device__ __forceinline__ float reduce16(float* p, int lane) {
    float q[8];
    {
        bool hi = (lane & 32) != 0;
        #pragma unroll
        for (int i = 0; i < 8; ++i) {
            float snd = hi ? p[i] : p[i + 8];
            float r = __shfl_xor(snd, 32, 64);
            q[i] = (hi ? p[i + 8] : p[i]) + r;
        }
    }
    float s4[4];
    {
        bool hi = (lane & 16) != 0;
        #pragma unroll
        for (int i = 0; i < 4; ++i) {
            float snd = hi ? q[i] : q[i + 4];
            float r = __shfl_xor(snd, 16, 64);
            s4[i] = (hi ? q[i + 4] : q[i]) + r;
        }
    }
    float d2[2];
    {
        bool hi = (lane & 8) != 0;
        #pragma unroll
        for (int i = 0; i < 2; ++i) {
            float snd = hi ? s4[i] : s4[i + 2];
            float r = __shfl_xor(snd, 8, 64);
            d2[i] = (hi ? s4[i + 2] : s4[i]) + r;
        }
    }
    float v;
    {
        bool hi = (lane & 4) != 0;
        float snd = hi ? d2[0] : d2[1];
        float r = __shfl_xor(snd, 4, 64);
        v = (hi ? d2[1] : d2[0]) + r;
    }
    v += __shfl_xor(v, 2, 64);
    v += __shfl_xor(v, 1, 64);
    return v;
}

__device__ __forceinline__ float gatedotR(const f8* A, const f8& w, int lane) {
    float p[16];
    #pragma unroll
    for (int b = 0; b < 16; ++b) p[b] = dot8(A[b], w);
    return reduce16(p, lane);
}
__device__ __forceinline__ float gatedotL(const float* act, const f8& w, int lane) {
    float p[16];
    #pragma unroll
    for (int b = 0; b < 16; ++b) {
        f8 r = ld8s(act + b * 512, lane);
        p[b] = dot8(r, w);
    }
    return reduce16(p, lane);
}
__device__ __forceinline__ void ldacts(f8* A, const float* act, int lane) {
    #pragma unroll
    for (int b = 0; b < 16; ++b) A[b] = ld8s(act + b * 512, lane);
}

// ---- store-slot barrier (r11/r14-proven).
__device__ __forceinline__ void barArrive(unsigned* slots, int sidx, unsigned tgt) {
    asm volatile("s_waitcnt vmcnt(0)" ::: "memory");
    __syncthreads();
    if (threadIdx.x == 0) stU(slots + sidx, tgt);
}
__device__ __forceinline__ void gridWait(unsigned* slots, unsigned tgt) {
    if (threadIdx.x < 64) {
        const unsigned* base = slots + threadIdx.x * 4;
        for (;;) {
            bool ok = (ldU(base + 0) >= tgt) & (ldU(base + 1) >= tgt)
                    & (ldU(base + 2) >= tgt) & (ldU(base + 3) >= tgt);
            if (__all(ok)) break;
            __builtin_amdgcn_s_sleep(1);
        }
    }
    __syncthreads();
}
__device__ __forceinline__ void groupWait(unsigned* slots, int gbase, unsigned tgt) {
    if (threadIdx.x < 64) {
        const unsigned* ps = slots + gbase + (threadIdx.x & 7);
        for (;;) {
            bool ok = ldU(ps) >= tgt;
            if (__all(ok)) break;
            __builtin_amdgcn_s_sleep(1);
        }
    }
    __syncthreads();
}

// ---------------------------------------------------------------------------
// k_pre (proven r1-r16, unchanged; 256 threads)
// ---------------------------------------------------------------------------
__global__ void k_pre(const float* __restrict__ emb, const float* __restrict__ io,
                      const float* __restrict__ Wih, const float* __restrict__ bih,
                      const float* __restrict__ bhh, float* __restrict__ pre)
{
    __shared__ float As[16][65];
    __shared__ float Bs[16][65];
    int tid = threadIdx.x;
    int row0 = blockIdx.y * 64;
    int col0 = blockIdx.x * 64;
    int ty = tid >> 4, tx = tid & 15;
    float acc[4][4] = {};
    int lr = tid >> 2;
    int lk4 = (tid & 3) * 4;
    for (int k0 = 0; k0 < 1024; k0 += 16) {
        int grow = row0 + lr;
        int b = grow & 15;
        #pragma unroll
        for (int q = 0; q < 4; ++q) {
            int k = k0 + lk4 + q;
            float v = (k < RR) ? emb[(size_t)grow * RR + k]
                               : io[(size_t)b * RR + (k - RR)];
            As[lk4 + q][lr] = v;
        }
        #pragma unroll
        for (int q = 0; q < 4; ++q) {
            int k = k0 + lk4 + q;
            Bs[lk4 + q][lr] = Wih[(size_t)(col0 + lr) * 1024 + k];
        }
        __syncthreads();
        #pragma unroll
        for (int kk = 0; kk < 16; ++kk) {
            float a[4], bbv[4];
            #pragma unroll
            for (int i = 0; i < 4; ++i) a[i] = As[kk][ty * 4 + i];
            #pragma unroll
            for (int j = 0; j < 4; ++j) bbv[j] = Bs[kk][tx * 4 + j];
            #pragma unroll
            for (int i = 0; i < 4; ++i)
                #pragma unroll
                for (int j = 0; j < 4; ++j)
                    acc[i][j] += a[i] * bbv[j];
        }
        __syncthreads();
    }
    #pragma unroll
    for (int i = 0; i < 4; ++i) {
        int grow = row0 + ty * 4 + i;
        #pragma unroll
        for (int j = 0; j < 4; ++j) {
            int gcol = col0 + tx * 4 + j;
            pre[(size_t)grow * 2048 + gcol] = acc[i][j] + bih[gcol] + bhh[gcol];
        }
    }
}

struct P {
    const float *pre, *Whh_r, *Wc, *bc, *Wih_w, *Whh_w, *bih_w, *bhh_w;
    const float *hr0, *cr0, *hw0, *cw0, *M0;
    float *mbuf, *comppre, *mpart, *mxpart, *sumpart;
    float *hrb0, *hrb1, *crS, *hwb0, *hwb1, *cwS;
    float *outputs, *Mw;
    unsigned *slots;
};

// ---------------------------------------------------------------------------
// Persistent kernel: 64-step recurrence; 256 blocks x 512 threads (8 waves).
// Each wave owns ONE gate-row (8 = 4 gates x 2 cols); stage A = 4 M-rows/wave.
// ---------------------------------------------------------------------------
__global__ void __launch_bounds__(512, 1) k_persist(P p)
{
    const int tid = threadIdx.x;
    const int bid = blockIdx.x;
    const int wv = tid >> 6;             // 0..7
    const int lane = tid & 63;
    const int u0 = bid * 2;
    const int kb = (bid & 7) * 4 + (bid >> 6);   // (k,b) group
    const int w2 = (bid >> 3) & 7;               // slot within group
    const int bM = kb & 15;
    const int rowG = kb * 256 + w2 * 32;
    const int sidx = kb * 8 + w2;
    const int gbase = kb * 8;

    // per-wave gate-row: gate = wv>>1, col offset uu = wv&1
    const int gateW = wv >> 1, uuW = wv & 1;
    const int jAw = gateW * 512 + u0 + uuW;

    __shared__ float Mlds[32][512];       // 64 KB
    __shared__ float bufH[16 * 512];      // 32 KB: hr_t; E overlay in D
    __shared__ float bufW[16 * 512];      // 32 KB: hw_{t-1}
    __shared__ float smacc[8][512];       // 16 KB
    __shared__ float smx8[8], ssh8[8];
    __shared__ float simL[32];
    __shared__ float gsm[2][4][16];       // [uu][gate][b]
    __shared__ float cc[2][3][16];        // [jj][item][b]
    __shared__ float wmx[16][2], wsm[16][2];
    __shared__ float bcsh[2];

    unsigned tg = 0;
    float mxK = 0.f, sumInvK = 0.f;
    float crR = 0.f, cwR = 0.f;

    // ---- per-wave register weights (one gate-row each)
    const f8 wRj = ld8s(p.Whh_r + (size_t)jAw * 512, lane);
    const f8 wWj = ld8s(p.Whh_w + (size_t)jAw * 512, lane);
    const f8 wIj = ld8s(p.Wih_w + (size_t)jAw * 512, lane);
    const float bwj = p.bih_w[jAw] + p.bhh_w[jAw];
    // stage-C role: waves 0-5: jj = col, item 0=hr,1=m0,2=m1
    const int jjC = (wv < 2) ? wv : ((wv < 4) ? wv - 2 : wv - 4);
    const int itmC = (wv < 2) ? 0 : ((wv < 4) ? 1 : 2);
    f8 wCj = {};
    if (wv < 6)
        wCj = ld8s(p.Wc + (size_t)(u0 + jjC) * 1536 + itmC * 512, lane);
    if (tid < 2) bcsh[tid] = p.bc[u0 + tid];
    if (tid < 32) cwR = p.cw0[(tid & 15) * 512 + u0 + (tid >> 4)];

    // ---- load this block's M rows: global M0 -> LDS (once)
    {
        const float4* src = (const float4*)(p.M0 + (size_t)rowG * 512);
        float4* dst = (float4*)&Mlds[0][0];
        #pragma unroll 2
        for (int idx = tid; idx < 32 * 128; idx += 512)
            dst[idx] = src[idx];
    }

    // ---- prologue: read-LSTM step 0 -> hr_0 (hrb0), cr_0 (register)
    {
        f8 A[16]; ldacts(A, p.hr0, lane);
        float gv = gatedotR(A, wRj, lane);
        if ((lane & 3) == 0) {
            int b = (lane >> 2) & 15;
            gsm[uuW][gateW][b] = gv + p.pre[(size_t)b * 2048 + jAw];
        }
        __syncthreads();
        if (tid < 32) {
            int b = tid & 15, uu = tid >> 4;
            int u = u0 + uu;
            float gi = sigmoidf_(gsm[uu][0][b]);
            float gf = sigmoidf_(gsm[uu][1][b]);
            float gg = tanhf(gsm[uu][2][b]);
            float go = sigmoidf_(gsm[uu][3][b]);
            float c = gf * p.cr0[b * 512 + u] + gi * gg;
            crR = c;
            stA(p.hrb0 + b * 512 + u, go * tanhf(c));
        }
        ++tg; barArrive(p.slots, sidx, tg); gridWait(p.slots, tg);
    }

    for (int t = 0; t < TT; ++t) {
        const float* hrcur  = (t & 1) ? p.hrb1 : p.hrb0;
        float*       hrnext = (t & 1) ? p.hrb0 : p.hrb1;
        const float* hwprev = (t == 0) ? p.hw0 : (((t - 1) & 1) ? p.hwb1 : p.hwb0);
        float*       hwnext = (t & 1) ? p.hwb1 : p.hwb0;

        // ---- stage hr_t AND hw_{t-1} in ONE coherent batch (1 round trip)
        {
            float4 st[8];
            const float* h0 = hrcur + tid * 4;
            const float* g0 = hwprev + tid * 4;
            LDG8(st[0], st[1], st[2], st[3], st[4], st[5], st[6], st[7],
                 h0, h0 + 2048, h0 + 4096, h0 + 6144,
                 g0, g0 + 2048, g0 + 4096, g0 + 6144);
            #pragma unroll
            for (int q = 0; q < 4; ++q) {
                ((float4*)bufH)[q * 512 + tid] = st[q];
                ((float4*)bufW)[q * 512 + tid] = st[4 + q];
            }
        }
        __syncthreads();

        // ========= stage A: deferred M update (local z) + sim + online partials
        {
            f8 h = ld8s(bufH + bM * 512, lane);
            f8 w8 = {};
            if (t > 0) w8 = ld8s(bufW + bM * 512, lane);
            float mx = -3.0e38f, ssum = 0.f;
            f8 macc = {};
            #pragma unroll
            for (int ii = 0; ii < 4; ++ii) {
                int rl = wv * 4 + ii;
                float4* mp0 = (float4*)&Mlds[rl][lane * 4];
                float4* mp1 = (float4*)&Mlds[rl][256 + lane * 4];
                f8 m; m.a = *mp0; m.b = *mp1;
                if (t > 0) {
                    float zf = 1.0f - __expf(simL[rl] - mxK) * sumInvK;
                    upd8(m, w8, zf);
                    *mp0 = m.a; *mp1 = m.b;
                }
                float s = wave_sum(dot8(m, h));
                float nmx = fmaxf(mx, s);
                float sc = __expf(mx - nmx);
                float wgt = __expf(s - nmx);
                fmaacc8(macc, sc, m, wgt);
                ssum = ssum * sc + wgt;
                mx = nmx;
                if (lane == 0) simL[rl] = s;
            }
            if (lane == 0) { smx8[wv] = mx; ssh8[wv] = ssum; }
            __syncthreads();
            float MXb = smx8[0];
            #pragma unroll
            for (int w3 = 1; w3 < 8; ++w3) MXb = fmaxf(MXb, smx8[w3]);
            float sc2 = __expf(mx - MXb);
            float* d0 = &smacc[wv][lane * 4];
            float* d1 = &smacc[wv][256 + lane * 4];
            d0[0] = macc.a.x * sc2; d0[1] = macc.a.y * sc2;
            d0[2] = macc.a.z * sc2; d0[3] = macc.a.w * sc2;
            d1[0] = macc.b.x * sc2; d1[1] = macc.b.y * sc2;
            d1[2] = macc.b.z * sc2; d1[3] = macc.b.w * sc2;
            __syncthreads();
            if (tid < 256) {
                int r2 = tid * 2;
                float s0 = 0.f, s1 = 0.f;
                #pragma unroll
                for (int w3 = 0; w3 < 8; ++w3) {
                    s0 += smacc[w3][r2];
                    s1 += smacc[w3][r2 + 1];
                }
                stA2(&p.mpart[(size_t)(kb * 8 + w2) * 512 + r2], s0, s1);
            }
            if (tid == 0) {
                float sB = 0.f;
                #pragma unroll
                for (int w3 = 0; w3 < 8; ++w3)
                    sB += ssh8[w3] * __expf(smx8[w3] - MXb);
                stA(&p.mxpart[kb * 8 + w2], MXb);
                stA(&p.sumpart[kb * 8 + w2], sB);
            }
        }
        // ========= stage A2: read-LSTM gates for t+1 (one gate-row per wave)
        if (t < 63) {
            float gv = gatedotL(bufH, wRj, lane);
            if ((lane & 3) == 0) {
                int b = (lane >> 2) & 15;
                gsm[uuW][gateW][b] = gv + p.pre[(size_t)((t + 1) * 16 + b) * 2048 + jAw];
            }
            __syncthreads();
            if (tid < 32) {
                int b = tid & 15, uu = tid >> 4;
                int u = u0 + uu;
                float gi = sigmoidf_(gsm[uu][0][b]);
                float gf = sigmoidf_(gsm[uu][1][b]);
                float gg = tanhf(gsm[uu][2][b]);
                float go = sigmoidf_(gsm[uu][3][b]);
                float c = gf * crR + gi * gg;
                crR = c;
                stA(hrnext + b * 512 + u, go * tanhf(c));
            }
        }

        // ========= stage B-lite: group (k,b) softmax stats + mbuf slice
        ++tg; barArrive(p.slots, sidx, tg); groupWait(p.slots, gbase, tg);
        {
            float mxp[8];
            #pragma unroll
            for (int w3 = 0; w3 < 8; ++w3) mxp[w3] = ldA(&p.mxpart[kb * 8 + w3]);
            float MX = -3.0e38f;
            #pragma unroll
            for (int w3 = 0; w3 < 8; ++w3) MX = fmaxf(MX, mxp[w3]);
            float SUM = 0.f;
            #pragma unroll
            for (int w3 = 0; w3 < 8; ++w3)
                SUM += ldA(&p.sumpart[kb * 8 + w3]) * __expf(mxp[w3] - MX);
            mxK = MX;
            sumInvK = 1.0f / SUM;
            if (tid < 32) {
                int r2 = w2 * 64 + tid * 2;
                float a0 = 0.f, a1 = 0.f;
                #pragma unroll
                for (int w3 = 0; w3 < 8; ++w3) {
                    float cf = __expf(mxp[w3] - MX);
                    float2 v2 = ldA2(&p.mpart[(size_t)(kb * 8 + w3) * 512 + r2]);
                    a0 += cf * v2.x;
                    a1 += cf * v2.y;
                }
                stA2(&p.mbuf[(size_t)kb * 512 + r2], a0 * sumInvK, a1 * sumInvK);
            }
        }
        ++tg; barArrive(p.slots, sidx, tg); gridWait(p.slots, tg);

        // ========= stage C: vh (all 8 waves, own row) + comp split 6 ways
        float vhJ = gatedotL(bufW, wWj, lane);
        {
            if (wv < 2) {
                float v = gatedotL(bufH, wCj, lane);
                if ((lane & 3) == 0) cc[jjC][0][(lane >> 2) & 15] = v;
            } else if (wv < 6) {
                f8 Am[16];
                const float* msbase = p.mbuf + (itmC - 1) * 16 * 512 + lane * 4;
                LDG16O(Am[0].a, Am[0].b, Am[1].a, Am[1].b,
                       Am[2].a, Am[2].b, Am[3].a, Am[3].b,
                       Am[4].a, Am[4].b, Am[5].a, Am[5].b,
                       Am[6].a, Am[6].b, Am[7].a, Am[7].b,
                       msbase, msbase + 1024, msbase + 2048, msbase + 3072);
                LDG16O(Am[8].a, Am[8].b, Am[9].a, Am[9].b,
                       Am[10].a, Am[10].b, Am[11].a, Am[11].b,
                       Am[12].a, Am[12].b, Am[13].a, Am[13].b,
                       Am[14].a, Am[14].b, Am[15].a, Am[15].b,
                       msbase + 4096, msbase + 5120, msbase + 6144, msbase + 7168);
                float v = gatedotR(Am, wCj, lane);
                if ((lane & 3) == 0) cc[jjC][itmC][(lane >> 2) & 15] = v;
            }
            __syncthreads();
            if (tid < 32) {
                int b = tid & 15, jj2 = tid >> 4;
                stA(&p.comppre[b * 512 + (u0 + jj2)],
                    cc[jj2][0][b] + cc[jj2][1][b] + cc[jj2][2][b] + bcsh[jj2]);
            }
        }
        ++tg; barArrive(p.slots, sidx, tg); gridWait(p.slots, tg);

        // ========= stage D: cooperative softmax -> E in bufH overlay;
        // write-LSTM gates (one gate-row per wave)
        {
            float4 v4[4];
            const float* cs = p.comppre + tid * 4;
            LDG4(v4[0], v4[1], v4[2], v4[3],
                 cs, cs + 2048, cs + 4096, cs + 6144);
            const int bhalf = wv & 1, brow = wv >> 1;
            #pragma unroll
            for (int k = 0; k < 4; ++k) {
                float mk = fmaxf(fmaxf(v4[k].x, v4[k].y), fmaxf(v4[k].z, v4[k].w));
                mk = wave_max(mk);
                if (lane == 0) wmx[k * 4 + brow][bhalf] = mk;
            }
            __syncthreads();                 // bufH (hr) reads all done
            float4* Eld4 = (float4*)bufH;
            #pragma unroll
            for (int k = 0; k < 4; ++k) {
                int b = k * 4 + brow;
                float mxb = fmaxf(wmx[b][0], wmx[b][1]);
                float e0 = __expf(v4[k].x - mxb), e1 = __expf(v4[k].y - mxb);
                float e2 = __expf(v4[k].z - mxb), e3 = __expf(v4[k].w - mxb);
                Eld4[k * 512 + tid] = make_float4(e0, e1, e2, e3);
                float sv = wave_sum(e0 + e1 + e2 + e3);
                if (lane == 0) wsm[b][bhalf] = sv;
            }
            __syncthreads();
            float ti = gatedotL(bufH, wIj, lane);
            if ((lane & 3) == 0) {
                int bb = (lane >> 2) & 15;
                float siv = 1.0f / (wsm[bb][0] + wsm[bb][1]);
                gsm[uuW][gateW][bb] = ti * siv + vhJ + bwj;
            }
            __syncthreads();
            if (tid < 32) {
                int bb = tid & 15, uu = tid >> 4;
                int u = u0 + uu;
                float gi = sigmoidf_(gsm[uu][0][bb]);
                float gf = sigmoidf_(gsm[uu][1][bb]);
                float gg = tanhf(gsm[uu][2][bb]);
                float go = sigmoidf_(gsm[uu][3][bb]);
                float c = gf * cwR + gi * gg;
                cwR = c;
                float h = go * tanhf(c);
                stA(hwnext + bb * 512 + u, h);
                p.outputs[(size_t)t * 8192 + bb * 512 + u] = h;
            }
        }
        ++tg; barArrive(p.slots, sidx, tg); gridWait(p.slots, tg);
    }

    // ---- epilogue: final deferred M update with (z_63, hw_63 = hwb1);
    //      write LDS M -> Mf; flush cr/cw registers to d_out
    {
        f8 w8 = ld8sA2(p.hwb1 + (size_t)bM * 512, lane);
        #pragma unroll
        for (int ii = 0; ii < 4; ++ii) {
            int rl = wv * 4 + ii;
            float zf = 1.0f - __expf(simL[rl] - mxK) * sumInvK;
            f8 m;
            m.a = *(float4*)&Mlds[rl][lane * 4];
            m.b = *(float4*)&Mlds[rl][256 + lane * 4];
            upd8(m, w8, zf);
            st8s(p.Mw + (size_t)(rowG + rl) * 512, m, lane);
        }
        if (tid < 32) {
            int b = tid & 15, uu = tid >> 4;
            int u = u0 + uu;
            p.crS[b * 512 + u] = crR;
            p.cwS[b * 512 + u] = cwR;
        }
    }
}

extern "C" void kernel_launch(void* const* d_in, const int* in_sizes, int n_in,
                              void* d_out, int out_size, void* d_ws, size_t ws_size,
                              hipStream_t stream) {
    const float* emb   = (const float*)d_in[0];
    const float* hr0   = (const float*)d_in[1];
    const float* cr0   = (const float*)d_in[2];
    const float* hw0   = (const float*)d_in[3];
    const float* cw0   = (const float*)d_in[4];
    const float* io    = (const float*)d_in[5];
    const float* M0    = (const float*)d_in[6];
    const float* Wih_r = (const float*)d_in[7];
    const float* bih_r = (const float*)d_in[9];
    const float* bhh_r = (const float*)d_in[10];

    float* out = (float*)d_out;
    float* outputs = out;                    // [64][16][512]
    float* hrS1 = out + 524288;              // hr slot = hr parity-1 buf
    float* crS  = out + 532480;
    float* hwS1 = out + 540672;              // hw slot = hw parity-1 buf
    float* cwS  = out + 548864;
    float* Mw   = out + 557056;              // Mf (written once at epilogue)

    float* ws = (float*)d_ws;
    float* pre     = ws;                     // 1024*2048
    float* mbuf    = ws + 2097152;           // 32*512
    float* comppre = mbuf + 16384;           // 16*512
    float* hrB0    = comppre + 8192;         // hr parity 0
    float* hwB0    = hrB0 + 8192;            // hw parity 0
    float* mpart   = hwB0 + 8192;            // 256*512
    float* mxpart  = mpart + 131072;         // 256
    float* sumpart = mxpart + 256;           // 256
    unsigned* slots = (unsigned*)(sumpart + 256); // 256 uints

    (void)hipMemsetAsync(slots, 0, 256 * sizeof(unsigned), stream);

    k_pre<<<dim3(32, 16), 256, 0, stream>>>(emb, io, Wih_r, bih_r, bhh_r, pre);

    P p;
    p.pre = pre;
    p.Whh_r = (const float*)d_in[8];
    p.Wc    = (const float*)d_in[11];
    p.bc    = (const float*)d_in[12];
    p.Wih_w = (const float*)d_in[13];
    p.Whh_w = (const float*)d_in[14];
    p.bih_w = (const float*)d_in[15];
    p.bhh_w = (const float*)d_in[16];
    p.hr0 = hr0; p.cr0 = cr0; p.hw0 = hw0; p.cw0 = cw0; p.M0 = M0;
    p.mbuf = mbuf; p.comppre = comppre;
    p.mpart = mpart; p.mxpart = mxpart; p.sumpart = sumpart;
    p.hrb0 = hrB0; p.hrb1 = hrS1; p.crS = crS;
    p.hwb0 = hwB0; p.hwb1 = hwS1; p.cwS = cwS;
    p.outputs = outputs; p.Mw = Mw;
    p.slots = slots;

    k_persist<<<NBLK, 512, 0, stream>>>(p);
}

// Round 18
// 1592.524 us; speedup vs baseline: 1.2332x; 1.0338x over previous
//
#include <hip/hip_runtime.h>
#include <math.h>

#define RR 512
#define BB 16
#define TT 64
#define KC 2
#define NN 256
#define NBLK 256

__device__ __forceinline__ float sigmoidf_(float x) {
    return 1.0f / (1.0f + __expf(-x));
}
__device__ __forceinline__ float wave_sum(float v) {
    #pragma unroll
    for (int off = 32; off > 0; off >>= 1) v += __shfl_xor(v, off, 64);
    return v;
}
__device__ __forceinline__ float wave_max(float v) {
    #pragma unroll
    for (int off = 32; off > 0; off >>= 1) v = fmaxf(v, __shfl_xor(v, off, 64));
    return v;
}

// ---- relaxed agent-scope atomic ops (MALL-coherent, no cache fences) ----
__device__ __forceinline__ float ldA(const float* p) {
    return __hip_atomic_load(p, __ATOMIC_RELAXED, __HIP_MEMORY_SCOPE_AGENT);
}
__device__ __forceinline__ void stA(float* p, float v) {
    __hip_atomic_store(p, v, __ATOMIC_RELAXED, __HIP_MEMORY_SCOPE_AGENT);
}
__device__ __forceinline__ unsigned ldU(const unsigned* p) {
    return __hip_atomic_load(p, __ATOMIC_RELAXED, __HIP_MEMORY_SCOPE_AGENT);
}
__device__ __forceinline__ void stU(unsigned* p, unsigned v) {
    __hip_atomic_store(p, v, __ATOMIC_RELAXED, __HIP_MEMORY_SCOPE_AGENT);
}
__device__ __forceinline__ float2 ldA2(const float* p) {
    unsigned long long v = __hip_atomic_load((const unsigned long long*)p,
                                             __ATOMIC_RELAXED, __HIP_MEMORY_SCOPE_AGENT);
    float2 r;
    r.x = __uint_as_float((unsigned)v);
    r.y = __uint_as_float((unsigned)(v >> 32));
    return r;
}
__device__ __forceinline__ void stA2(float* p, float x, float y) {
    unsigned long long v = ((unsigned long long)__float_as_uint(y) << 32)
                         | (unsigned long long)__float_as_uint(x);
    __hip_atomic_store((unsigned long long*)p, v, __ATOMIC_RELAXED,
                       __HIP_MEMORY_SCOPE_AGENT);
}

// ---- coherent dwordx4 batches, waitcnt INSIDE each asm (r14-proven).
// Flat 64-bit vaddr only (r15 lesson: "s" constraints may land in VGPRs).
#define LDG8(d0,d1,d2,d3,d4,d5,d6,d7, q0,q1,q2,q3,q4,q5,q6,q7)      \
    asm volatile(                                                     \
        "global_load_dwordx4 %0, %8, off sc0 sc1\n\t"                \
        "global_load_dwordx4 %1, %9, off sc0 sc1\n\t"                \
        "global_load_dwordx4 %2, %10, off sc0 sc1\n\t"               \
        "global_load_dwordx4 %3, %11, off sc0 sc1\n\t"               \
        "global_load_dwordx4 %4, %12, off sc0 sc1\n\t"               \
        "global_load_dwordx4 %5, %13, off sc0 sc1\n\t"               \
        "global_load_dwordx4 %6, %14, off sc0 sc1\n\t"               \
        "global_load_dwordx4 %7, %15, off sc0 sc1\n\t"               \
        "s_waitcnt vmcnt(0)"                                          \
        : "=&v"(d0), "=&v"(d1), "=&v"(d2), "=&v"(d3),                 \
          "=&v"(d4), "=&v"(d5), "=&v"(d6), "=&v"(d7)                  \
        : "v"(q0), "v"(q1), "v"(q2), "v"(q3),                         \
          "v"(q4), "v"(q5), "v"(q6), "v"(q7)                          \
        : "memory")

#define LDG4(d0,d1,d2,d3, q0,q1,q2,q3)                                \
    asm volatile(                                                     \
        "global_load_dwordx4 %0, %4, off sc0 sc1\n\t"                \
        "global_load_dwordx4 %1, %5, off sc0 sc1\n\t"                \
        "global_load_dwordx4 %2, %6, off sc0 sc1\n\t"                \
        "global_load_dwordx4 %3, %7, off sc0 sc1\n\t"                \
        "s_waitcnt vmcnt(0)"                                          \
        : "=&v"(d0), "=&v"(d1), "=&v"(d2), "=&v"(d3)                  \
        : "v"(q0), "v"(q1), "v"(q2), "v"(q3)                          \
        : "memory")

#define LDG2(d0,d1, q0,q1)                                            \
    asm volatile(                                                     \
        "global_load_dwordx4 %0, %2, off sc0 sc1\n\t"                \
        "global_load_dwordx4 %1, %3, off sc0 sc1\n\t"                \
        "s_waitcnt vmcnt(0)"                                          \
        : "=&v"(d0), "=&v"(d1)                                        \
        : "v"(q0), "v"(q1)                                            \
        : "memory")

// 16 loads from 4 flat addresses x offset:{0,1024,2048,3072}; ONE wait.
#define LDG16O(d0,d1,d2,d3,d4,d5,d6,d7,d8,d9,d10,d11,d12,d13,d14,d15,\
               q0,q1,q2,q3)                                           \
    asm volatile(                                                     \
        "global_load_dwordx4 %0, %16, off sc0 sc1\n\t"               \
        "global_load_dwordx4 %1, %16, off offset:1024 sc0 sc1\n\t"   \
        "global_load_dwordx4 %2, %16, off offset:2048 sc0 sc1\n\t"   \
        "global_load_dwordx4 %3, %16, off offset:3072 sc0 sc1\n\t"   \
        "global_load_dwordx4 %4, %17, off sc0 sc1\n\t"               \
        "global_load_dwordx4 %5, %17, off offset:1024 sc0 sc1\n\t"   \
        "global_load_dwordx4 %6, %17, off offset:2048 sc0 sc1\n\t"   \
        "global_load_dwordx4 %7, %17, off offset:3072 sc0 sc1\n\t"   \
        "global_load_dwordx4 %8, %18, off sc0 sc1\n\t"               \
        "global_load_dwordx4 %9, %18, off offset:1024 sc0 sc1\n\t"   \
        "global_load_dwordx4 %10, %18, off offset:2048 sc0 sc1\n\t"  \
        "global_load_dwordx4 %11, %18, off offset:3072 sc0 sc1\n\t"  \
        "global_load_dwordx4 %12, %19, off sc0 sc1\n\t"              \
        "global_load_dwordx4 %13, %19, off offset:1024 sc0 sc1\n\t"  \
        "global_load_dwordx4 %14, %19, off offset:2048 sc0 sc1\n\t"  \
        "global_load_dwordx4 %15, %19, off offset:3072 sc0 sc1\n\t"  \
        "s_waitcnt vmcnt(0)"                                          \
        : "=&v"(d0), "=&v"(d1), "=&v"(d2), "=&v"(d3),                 \
          "=&v"(d4), "=&v"(d5), "=&v"(d6), "=&v"(d7),                 \
          "=&v"(d8), "=&v"(d9), "=&v"(d10), "=&v"(d11),               \
          "=&v"(d12), "=&v"(d13), "=&v"(d14), "=&v"(d15)              \
        : "v"(q0), "v"(q1), "v"(q2), "v"(q3)                          \
        : "memory")

struct f8 { float4 a, b; };
// split-slice mapping: lane's 8 floats of a 512-row = [lane*4,+4) and
// [256+lane*4,+4). Conflict-free LDS b128.
__device__ __forceinline__ f8 ld8s(const float* row, int lane) {
    f8 r;
    r.a = *(const float4*)(row + lane * 4);
    r.b = *(const float4*)(row + 256 + lane * 4);
    return r;
}
__device__ __forceinline__ void st8s(float* row, const f8& v, int lane) {
    *(float4*)(row + lane * 4) = v.a;
    *(float4*)(row + 256 + lane * 4) = v.b;
}
__device__ __forceinline__ f8 ld8sA2(const float* row, int lane) {
    float2 t0 = ldA2(row + lane * 4);
    float2 t1 = ldA2(row + lane * 4 + 2);
    float2 t2 = ldA2(row + 256 + lane * 4);
    float2 t3 = ldA2(row + 256 + lane * 4 + 2);
    f8 r;
    r.a = make_float4(t0.x, t0.y, t1.x, t1.y);
    r.b = make_float4(t2.x, t2.y, t3.x, t3.y);
    return r;
}
__device__ __forceinline__ float dot8(const f8& x, const f8& y) {
    return x.a.x*y.a.x + x.a.y*y.a.y + x.a.z*y.a.z + x.a.w*y.a.w
         + x.b.x*y.b.x + x.b.y*y.b.y + x.b.z*y.b.z + x.b.w*y.b.w;
}
// inline function, NOT a macro (macro param `w` collides with float4::w)
__device__ __forceinline__ void upd8(f8& m, const f8& u, float zf) {
    m.a.x = zf * (m.a.x + u.a.x); m.a.y = zf * (m.a.y + u.a.y);
    m.a.z = zf * (m.a.z + u.a.z); m.a.w = zf * (m.a.w + u.a.w);
    m.b.x = zf * (m.b.x + u.b.x); m.b.y = zf * (m.b.y + u.b.y);
    m.b.z = zf * (m.b.z + u.b.z); m.b.w = zf * (m.b.w + u.b.w);
}
__device__ __forceinline__ void fmaacc8(f8& acc, float sc, const f8& m, float wgt) {
    acc.a.x = acc.a.x*sc + wgt*m.a.x; acc.a.y = acc.a.y*sc + wgt*m.a.y;
    acc.a.z = acc.a.z*sc + wgt*m.a.z; acc.a.w = acc.a.w*sc + wgt*m.a.w;
    acc.b.x = acc.b.x*sc + wgt*m.b.x; acc.b.y = acc.b.y*sc + wgt*m.b.y;
    acc.b.z = acc.b.z*sc + wgt*m.b.z; acc.b.w = acc.b.w*sc + wgt*m.b.w;
}

// Payload-halving butterfly: p[0..15] per-slot partials across 64 lanes ->
// each lane returns the full sum for slot = (lane>>2)&15.
__device__ __forceinline__ float reduce16(float* p, int lane) {
    float q[8];
    {
        bool hi = (lane & 32) != 0;
        #pragma unroll
        for (int i = 0; i < 8; ++i) {
            float snd = hi ? p[i] : p[i + 8];
            float r = __shfl_xor(snd, 32, 64);
            q[i] = (hi ? p[i + 8] : p[i]) + r;
        }
    }
    float s4[4];
    {
        bool hi = (lane & 16) != 0;
        #pragma unroll
        for (int i = 0; i < 4; ++i) {
            float snd = hi ? q[i] : q[i + 4];
            float r = __shfl_xor(snd, 16, 64);
            s4[i] = (hi ? q[i + 4] : q[i]) + r;
        }
    }
    float d2[2];
    {
        bool hi = (lane & 8) != 0;
        #pragma unroll
        for (int i = 0; i < 2; ++i) {
            float snd = hi ? s4[i] : s4[i + 2];
            float r = __shfl_xor(snd, 8, 64);
            d2[i] = (hi ? s4[i + 2] : s4[i]) + r;
        }
    }
    float v;
    {
        bool hi = (lane & 4) != 0;
        float snd = hi ? d2[0] : d2[1];
        float r = __shfl_xor(snd, 4, 64);
        v = (hi ? d2[1] : d2[0]) + r;
    }
    v += __shfl_xor(v, 2, 64);
    v += __shfl_xor(v, 1, 64);
    return v;
}

__device__ __forceinline__ float gatedotR(const f8* A, const f8& w, int lane) {
    float p[16];
    #pragma unroll
    for (int b = 0; b < 16; ++b) p[b] = dot8(A[b], w);
    return reduce16(p, lane);
}
__device__ __forceinline__ float gatedotL(const float* act, const f8& w, int lane) {
    float p[16];
    #pragma unroll
    for (int b = 0; b < 16; ++b) {
        f8 r = ld8s(act + b * 512, lane);
        p[b] = dot8(r, w);
    }
    return reduce16(p, lane);
}
__device__ __forceinline__ void ldacts(f8* A, const float* act, int lane) {
    #pragma unroll
    for (int b = 0; b < 16; ++b) A[b] = ld8s(act + b * 512, lane);
}

// ---- store-slot barrier (r11/r14-proven).
__device__ __forceinline__ void barArrive(unsigned* slots, int sidx, unsigned tgt) {
    asm volatile("s_waitcnt vmcnt(0)" ::: "memory");
    __syncthreads();
    if (threadIdx.x == 0) stU(slots + sidx, tgt);
}
__device__ __forceinline__ void gridWait(unsigned* slots, unsigned tgt) {
    if (threadIdx.x < 64) {
        const unsigned* base = slots + threadIdx.x * 4;
        for (;;) {
            bool ok = (ldU(base + 0) >= tgt) & (ldU(base + 1) >= tgt)
                    & (ldU(base + 2) >= tgt) & (ldU(base + 3) >= tgt);
            if (__all(ok)) break;
            __builtin_amdgcn_s_sleep(1);
        }
    }
    __syncthreads();
}
__device__ __forceinline__ void groupWait(unsigned* slots, int gbase, unsigned tgt) {
    if (threadIdx.x < 64) {
        const unsigned* ps = slots + gbase + (threadIdx.x & 7);
        for (;;) {
            bool ok = ldU(ps) >= tgt;
            if (__all(ok)) break;
            __builtin_amdgcn_s_sleep(1);
        }
    }
    __syncthreads();
}

// ---------------------------------------------------------------------------
// k_pre (proven r1-r17, unchanged; 256 threads)
// ---------------------------------------------------------------------------
__global__ void k_pre(const float* __restrict__ emb, const float* __restrict__ io,
                      const float* __restrict__ Wih, const float* __restrict__ bih,
                      const float* __restrict__ bhh, float* __restrict__ pre)
{
    __shared__ float As[16][65];
    __shared__ float Bs[16][65];
    int tid = threadIdx.x;
    int row0 = blockIdx.y * 64;
    int col0 = blockIdx.x * 64;
    int ty = tid >> 4, tx = tid & 15;
    float acc[4][4] = {};
    int lr = tid >> 2;
    int lk4 = (tid & 3) * 4;
    for (int k0 = 0; k0 < 1024; k0 += 16) {
        int grow = row0 + lr;
        int b = grow & 15;
        #pragma unroll
        for (int q = 0; q < 4; ++q) {
            int k = k0 + lk4 + q;
            float v = (k < RR) ? emb[(size_t)grow * RR + k]
                               : io[(size_t)b * RR + (k - RR)];
            As[lk4 + q][lr] = v;
        }
        #pragma unroll
        for (int q = 0; q < 4; ++q) {
            int k = k0 + lk4 + q;
            Bs[lk4 + q][lr] = Wih[(size_t)(col0 + lr) * 1024 + k];
        }
        __syncthreads();
        #pragma unroll
        for (int kk = 0; kk < 16; ++kk) {
            float a[4], bbv[4];
            #pragma unroll
            for (int i = 0; i < 4; ++i) a[i] = As[kk][ty * 4 + i];
            #pragma unroll
            for (int j = 0; j < 4; ++j) bbv[j] = Bs[kk][tx * 4 + j];
            #pragma unroll
            for (int i = 0; i < 4; ++i)
                #pragma unroll
                for (int j = 0; j < 4; ++j)
                    acc[i][j] += a[i] * bbv[j];
        }
        __syncthreads();
    }
    #pragma unroll
    for (int i = 0; i < 4; ++i) {
        int grow = row0 + ty * 4 + i;
        #pragma unroll
        for (int j = 0; j < 4; ++j) {
            int gcol = col0 + tx * 4 + j;
            pre[(size_t)grow * 2048 + gcol] = acc[i][j] + bih[gcol] + bhh[gcol];
        }
    }
}

struct P {
    const float *pre, *Whh_r, *Wc, *bc, *Wih_w, *Whh_w, *bih_w, *bhh_w;
    const float *hr0, *cr0, *hw0, *cw0, *M0;
    float *mbuf, *comppre, *mpart, *mxpart, *sumpart;
    float *hrb0, *hrb1, *crS, *hwb0, *hwb1, *cwS;
    float *outputs, *Mw;
    unsigned *slots;
};

// ---------------------------------------------------------------------------
// Persistent kernel: 64-step recurrence; 256 blocks x 512 threads (8 waves).
// sim dots for step t+1 precomputed in phase C (waves 6,7) via the linearity
// sim_{t+1} = (1-z_t)(Mlds·hr_{t+1} + hw_t·hr_{t+1}); stage A uses 1 wave_sum.
// ---------------------------------------------------------------------------
__global__ void __launch_bounds__(512, 1) k_persist(P p)
{
    const int tid = threadIdx.x;
    const int bid = blockIdx.x;
    const int wv = tid >> 6;             // 0..7
    const int lane = tid & 63;
    const int u0 = bid * 2;
    const int kb = (bid & 7) * 4 + (bid >> 6);   // (k,b) group
    const int w2 = (bid >> 3) & 7;               // slot within group
    const int bM = kb & 15;
    const int rowG = kb * 256 + w2 * 32;
    const int sidx = kb * 8 + w2;
    const int gbase = kb * 8;

    const int gateW = wv >> 1, uuW = wv & 1;
    const int jAw = gateW * 512 + u0 + uuW;

    __shared__ float Mlds[32][512];       // 64 KB
    __shared__ float bufH[16 * 512];      // 32 KB: hr_t; E overlay in D
    __shared__ float bufW[16 * 512];      // 32 KB: hw_{t-1}
    __shared__ float smacc[8][512];       // 16 KB
    __shared__ float smx8[8], ssh8[8];
    __shared__ float simL[32];            // sim_t (z source for t+1)
    __shared__ float dotN[32];            // precomputed Mlds·hr_{t+1}
    __shared__ float gsm[2][4][16];
    __shared__ float cc[2][3][16];
    __shared__ float wmx[16][2], wsm[16][2];
    __shared__ float bcsh[2];

    unsigned tg = 0;
    float mxK = 0.f, sumInvK = 0.f;
    float crR = 0.f, cwR = 0.f;

    const f8 wRj = ld8s(p.Whh_r + (size_t)jAw * 512, lane);
    const f8 wWj = ld8s(p.Whh_w + (size_t)jAw * 512, lane);
    const f8 wIj = ld8s(p.Wih_w + (size_t)jAw * 512, lane);
    const float bwj = p.bih_w[jAw] + p.bhh_w[jAw];
    const int jjC = (wv < 2) ? wv : ((wv < 4) ? wv - 2 : wv - 4);
    const int itmC = (wv < 2) ? 0 : ((wv < 4) ? 1 : 2);
    f8 wCj = {};
    if (wv < 6)
        wCj = ld8s(p.Wc + (size_t)(u0 + jjC) * 1536 + itmC * 512, lane);
    if (tid < 2) bcsh[tid] = p.bc[u0 + tid];
    if (tid < 32) cwR = p.cw0[(tid & 15) * 512 + u0 + (tid >> 4)];

    // ---- load this block's M rows: global M0 -> LDS (once)
    {
        const float4* src = (const float4*)(p.M0 + (size_t)rowG * 512);
        float4* dst = (float4*)&Mlds[0][0];
        #pragma unroll 2
        for (int idx = tid; idx < 32 * 128; idx += 512)
            dst[idx] = src[idx];
    }

    // ---- prologue: read-LSTM step 0 -> hr_0 (hrb0), cr_0 (register)
    {
        f8 A[16]; ldacts(A, p.hr0, lane);
        float gv = gatedotR(A, wRj, lane);
        if ((lane & 3) == 0) {
            int b = (lane >> 2) & 15;
            gsm[uuW][gateW][b] = gv + p.pre[(size_t)b * 2048 + jAw];
        }
        __syncthreads();
        if (tid < 32) {
            int b = tid & 15, uu = tid >> 4;
            int u = u0 + uu;
            float gi = sigmoidf_(gsm[uu][0][b]);
            float gf = sigmoidf_(gsm[uu][1][b]);
            float gg = tanhf(gsm[uu][2][b]);
            float go = sigmoidf_(gsm[uu][3][b]);
            float c = gf * p.cr0[b * 512 + u] + gi * gg;
            crR = c;
            stA(p.hrb0 + b * 512 + u, go * tanhf(c));
        }
        ++tg; barArrive(p.slots, sidx, tg); gridWait(p.slots, tg);
    }

    for (int t = 0; t < TT; ++t) {
        const float* hrcur  = (t & 1) ? p.hrb1 : p.hrb0;
        float*       hrnext = (t & 1) ? p.hrb0 : p.hrb1;
        const float* hwprev = (t == 0) ? p.hw0 : (((t - 1) & 1) ? p.hwb1 : p.hwb0);
        float*       hwnext = (t & 1) ? p.hwb1 : p.hwb0;

        // ---- stage hr_t AND hw_{t-1} in ONE coherent batch (1 round trip)
        {
            float4 st[8];
            const float* h0 = hrcur + tid * 4;
            const float* g0 = hwprev + tid * 4;
            LDG8(st[0], st[1], st[2], st[3], st[4], st[5], st[6], st[7],
                 h0, h0 + 2048, h0 + 4096, h0 + 6144,
                 g0, g0 + 2048, g0 + 4096, g0 + 6144);
            #pragma unroll
            for (int q = 0; q < 4; ++q) {
                ((float4*)bufH)[q * 512 + tid] = st[q];
                ((float4*)bufW)[q * 512 + tid] = st[4 + q];
            }
        }
        __syncthreads();

        // ========= stage A: deferred M update (local z) + sim (from dotN) +
        // online partials
        {
            f8 h = ld8s(bufH + bM * 512, lane);
            f8 w8 = {};
            float hwDot = 0.f;
            if (t > 0) {
                w8 = ld8s(bufW + bM * 512, lane);
                hwDot = wave_sum(dot8(w8, h));
            }
            float mx = -3.0e38f, ssum = 0.f;
            f8 macc = {};
            #pragma unroll
            for (int ii = 0; ii < 4; ++ii) {
                int rl = wv * 4 + ii;
                float4* mp0 = (float4*)&Mlds[rl][lane * 4];
                float4* mp1 = (float4*)&Mlds[rl][256 + lane * 4];
                f8 m; m.a = *mp0; m.b = *mp1;
                float s;
                if (t > 0) {
                    float zf = 1.0f - __expf(simL[rl] - mxK) * sumInvK;
                    upd8(m, w8, zf);
                    *mp0 = m.a; *mp1 = m.b;
                    s = zf * (dotN[rl] + hwDot);
                } else {
                    s = wave_sum(dot8(m, h));
                }
                float nmx = fmaxf(mx, s);
                float sc = __expf(mx - nmx);
                float wgt = __expf(s - nmx);
                fmaacc8(macc, sc, m, wgt);
                ssum = ssum * sc + wgt;
                mx = nmx;
                if (lane == 0) simL[rl] = s;
            }
            if (lane == 0) { smx8[wv] = mx; ssh8[wv] = ssum; }
            __syncthreads();
            float MXb = smx8[0];
            #pragma unroll
            for (int w3 = 1; w3 < 8; ++w3) MXb = fmaxf(MXb, smx8[w3]);
            float sc2 = __expf(mx - MXb);
            float* d0 = &smacc[wv][lane * 4];
            float* d1 = &smacc[wv][256 + lane * 4];
            d0[0] = macc.a.x * sc2; d0[1] = macc.a.y * sc2;
            d0[2] = macc.a.z * sc2; d0[3] = macc.a.w * sc2;
            d1[0] = macc.b.x * sc2; d1[1] = macc.b.y * sc2;
            d1[2] = macc.b.z * sc2; d1[3] = macc.b.w * sc2;
            __syncthreads();
            if (tid < 256) {
                int r2 = tid * 2;
                float s0 = 0.f, s1 = 0.f;
                #pragma unroll
                for (int w3 = 0; w3 < 8; ++w3) {
                    s0 += smacc[w3][r2];
                    s1 += smacc[w3][r2 + 1];
                }
                stA2(&p.mpart[(size_t)(kb * 8 + w2) * 512 + r2], s0, s1);
            }
            if (tid == 0) {
                float sB = 0.f;
                #pragma unroll
                for (int w3 = 0; w3 < 8; ++w3)
                    sB += ssh8[w3] * __expf(smx8[w3] - MXb);
                stA(&p.mxpart[kb * 8 + w2], MXb);
                stA(&p.sumpart[kb * 8 + w2], sB);
            }
        }
        // ========= stage A2: read-LSTM gates for t+1 (one gate-row per wave)
        if (t < 63) {
            float gv = gatedotL(bufH, wRj, lane);
            if ((lane & 3) == 0) {
                int b = (lane >> 2) & 15;
                gsm[uuW][gateW][b] = gv + p.pre[(size_t)((t + 1) * 16 + b) * 2048 + jAw];
            }
            __syncthreads();
            if (tid < 32) {
                int b = tid & 15, uu = tid >> 4;
                int u = u0 + uu;
                float gi = sigmoidf_(gsm[uu][0][b]);
                float gf = sigmoidf_(gsm[uu][1][b]);
                float gg = tanhf(gsm[uu][2][b]);
                float go = sigmoidf_(gsm[uu][3][b]);
                float c = gf * crR + gi * gg;
                crR = c;
                stA(hrnext + b * 512 + u, go * tanhf(c));
            }
        }

        // ========= stage B-lite: group (k,b) softmax stats + mbuf slice
        ++tg; barArrive(p.slots, sidx, tg); groupWait(p.slots, gbase, tg);
        {
            float mxp[8];
            #pragma unroll
            for (int w3 = 0; w3 < 8; ++w3) mxp[w3] = ldA(&p.mxpart[kb * 8 + w3]);
            float MX = -3.0e38f;
            #pragma unroll
            for (int w3 = 0; w3 < 8; ++w3) MX = fmaxf(MX, mxp[w3]);
            float SUM = 0.f;
            #pragma unroll
            for (int w3 = 0; w3 < 8; ++w3)
                SUM += ldA(&p.sumpart[kb * 8 + w3]) * __expf(mxp[w3] - MX);
            mxK = MX;
            sumInvK = 1.0f / SUM;
            if (tid < 32) {
                int r2 = w2 * 64 + tid * 2;
                float a0 = 0.f, a1 = 0.f;
                #pragma unroll
                for (int w3 = 0; w3 < 8; ++w3) {
                    float cf = __expf(mxp[w3] - MX);
                    float2 v2 = ldA2(&p.mpart[(size_t)(kb * 8 + w3) * 512 + r2]);
                    a0 += cf * v2.x;
                    a1 += cf * v2.y;
                }
                stA2(&p.mbuf[(size_t)kb * 512 + r2], a0 * sumInvK, a1 * sumInvK);
            }
        }
        ++tg; barArrive(p.slots, sidx, tg); gridWait(p.slots, tg);

        // ========= stage C: vh (all waves) + comp split (waves 0-5) +
        // dotN precompute for t+1 (waves 6,7; hr_{t+1} visible post-barrier)
        float vhJ = gatedotL(bufW, wWj, lane);
        {
            if (wv < 2) {
                float v = gatedotL(bufH, wCj, lane);
                if ((lane & 3) == 0) cc[jjC][0][(lane >> 2) & 15] = v;
            } else if (wv < 6) {
                f8 Am[16];
                const float* msbase = p.mbuf + (itmC - 1) * 16 * 512 + lane * 4;
                LDG16O(Am[0].a, Am[0].b, Am[1].a, Am[1].b,
                       Am[2].a, Am[2].b, Am[3].a, Am[3].b,
                       Am[4].a, Am[4].b, Am[5].a, Am[5].b,
                       Am[6].a, Am[6].b, Am[7].a, Am[7].b,
                       msbase, msbase + 1024, msbase + 2048, msbase + 3072);
                LDG16O(Am[8].a, Am[8].b, Am[9].a, Am[9].b,
                       Am[10].a, Am[10].b, Am[11].a, Am[11].b,
                       Am[12].a, Am[12].b, Am[13].a, Am[13].b,
                       Am[14].a, Am[14].b, Am[15].a, Am[15].b,
                       msbase + 4096, msbase + 5120, msbase + 6144, msbase + 7168);
                float v = gatedotR(Am, wCj, lane);
                if ((lane & 3) == 0) cc[jjC][itmC][(lane >> 2) & 15] = v;
            } else if (t < 63) {
                // dotN[rl] = Mlds[rl] . hr_{t+1}[bM]  (pre-update M: exact
                // via sim_{t+1} = zf*(dotN + hw_t.hr_{t+1}))
                f8 hN;
                const float* hp = hrnext + bM * 512;
                LDG2(hN.a, hN.b, hp + lane * 4, hp + 256 + lane * 4);
                float pp[16];
                int rbase = (wv - 6) * 16;
                #pragma unroll
                for (int r = 0; r < 16; ++r)
                    pp[r] = dot8(ld8s(&Mlds[rbase + r][0], lane), hN);
                float v = reduce16(pp, lane);
                if ((lane & 3) == 0) dotN[rbase + ((lane >> 2) & 15)] = v;
            }
            __syncthreads();
            if (tid < 32) {
                int b = tid & 15, jj2 = tid >> 4;
                stA(&p.comppre[b * 512 + (u0 + jj2)],
                    cc[jj2][0][b] + cc[jj2][1][b] + cc[jj2][2][b] + bcsh[jj2]);
            }
        }
        ++tg; barArrive(p.slots, sidx, tg); gridWait(p.slots, tg);

        // ========= stage D: cooperative softmax -> E in bufH overlay;
        // write-LSTM gates (one gate-row per wave)
        {
            float4 v4[4];
            const float* cs = p.comppre + tid * 4;
            LDG4(v4[0], v4[1], v4[2], v4[3],
                 cs, cs + 2048, cs + 4096, cs + 6144);
            const int bhalf = wv & 1, brow = wv >> 1;
            #pragma unroll
            for (int k = 0; k < 4; ++k) {
                float mk = fmaxf(fmaxf(v4[k].x, v4[k].y), fmaxf(v4[k].z, v4[k].w));
                mk = wave_max(mk);
                if (lane == 0) wmx[k * 4 + brow][bhalf] = mk;
            }
            __syncthreads();                 // bufH (hr) reads all done
            float4* Eld4 = (float4*)bufH;
            #pragma unroll
            for (int k = 0; k < 4; ++k) {
                int b = k * 4 + brow;
                float mxb = fmaxf(wmx[b][0], wmx[b][1]);
                float e0 = __expf(v4[k].x - mxb), e1 = __expf(v4[k].y - mxb);
                float e2 = __expf(v4[k].z - mxb), e3 = __expf(v4[k].w - mxb);
                Eld4[k * 512 + tid] = make_float4(e0, e1, e2, e3);
                float sv = wave_sum(e0 + e1 + e2 + e3);
                if (lane == 0) wsm[b][bhalf] = sv;
            }
            __syncthreads();
            float ti = gatedotL(bufH, wIj, lane);
            if ((lane & 3) == 0) {
                int bb = (lane >> 2) & 15;
                float siv = 1.0f / (wsm[bb][0] + wsm[bb][1]);
                gsm[uuW][gateW][bb] = ti * siv + vhJ + bwj;
            }
            __syncthreads();
            if (tid < 32) {
                int bb = tid & 15, uu = tid >> 4;
                int u = u0 + uu;
                float gi = sigmoidf_(gsm[uu][0][bb]);
                float gf = sigmoidf_(gsm[uu][1][bb]);
                float gg = tanhf(gsm[uu][2][bb]);
                float go = sigmoidf_(gsm[uu][3][bb]);
                float c = gf * cwR + gi * gg;
                cwR = c;
                float h = go * tanhf(c);
                stA(hwnext + bb * 512 + u, h);
                p.outputs[(size_t)t * 8192 + bb * 512 + u] = h;
            }
        }
        ++tg; barArrive(p.slots, sidx, tg); gridWait(p.slots, tg);
    }

    // ---- epilogue: final deferred M update with (z_63, hw_63 = hwb1);
    //      write LDS M -> Mf; flush cr/cw registers to d_out
    {
        f8 w8 = ld8sA2(p.hwb1 + (size_t)bM * 512, lane);
        #pragma unroll
        for (int ii = 0; ii < 4; ++ii) {
            int rl = wv * 4 + ii;
            float zf = 1.0f - __expf(simL[rl] - mxK) * sumInvK;
            f8 m;
            m.a = *(float4*)&Mlds[rl][lane * 4];
            m.b = *(float4*)&Mlds[rl][256 + lane * 4];
            upd8(m, w8, zf);
            st8s(p.Mw + (size_t)(rowG + rl) * 512, m, lane);
        }
        if (tid < 32) {
            int b = tid & 15, uu = tid >> 4;
            int u = u0 + uu;
            p.crS[b * 512 + u] = crR;
            p.cwS[b * 512 + u] = cwR;
        }
    }
}

extern "C" void kernel_launch(void* const* d_in, const int* in_sizes, int n_in,
                              void* d_out, int out_size, void* d_ws, size_t ws_size,
                              hipStream_t stream) {
    const float* emb   = (const float*)d_in[0];
    const float* hr0   = (const float*)d_in[1];
    const float* cr0   = (const float*)d_in[2];
    const float* hw0   = (const float*)d_in[3];
    const float* cw0   = (const float*)d_in[4];
    const float* io    = (const float*)d_in[5];
    const float* M0    = (const float*)d_in[6];
    const float* Wih_r = (const float*)d_in[7];
    const float* bih_r = (const float*)d_in[9];
    const float* bhh_r = (const float*)d_in[10];

    float* out = (float*)d_out;
    float* outputs = out;                    // [64][16][512]
    float* hrS1 = out + 524288;              // hr slot = hr parity-1 buf
    float* crS  = out + 532480;
    float* hwS1 = out + 540672;              // hw slot = hw parity-1 buf
    float* cwS  = out + 548864;
    float* Mw   = out + 557056;              // Mf (written once at epilogue)

    float* ws = (float*)d_ws;
    float* pre     = ws;                     // 1024*2048
    float* mbuf    = ws + 2097152;           // 32*512
    float* comppre = mbuf + 16384;           // 16*512
    float* hrB0    = comppre + 8192;         // hr parity 0
    float* hwB0    = hrB0 + 8192;            // hw parity 0
    float* mpart   = hwB0 + 8192;            // 256*512
    float* mxpart  = mpart + 131072;         // 256
    float* sumpart = mxpart + 256;           // 256
    unsigned* slots = (unsigned*)(sumpart + 256); // 256 uints

    (void)hipMemsetAsync(slots, 0, 256 * sizeof(unsigned), stream);

    k_pre<<<dim3(32, 16), 256, 0, stream>>>(emb, io, Wih_r, bih_r, bhh_r, pre);

    P p;
    p.pre = pre;
    p.Whh_r = (const float*)d_in[8];
    p.Wc    = (const float*)d_in[11];
    p.bc    = (const float*)d_in[12];
    p.Wih_w = (const float*)d_in[13];
    p.Whh_w = (const float*)d_in[14];
    p.bih_w = (const float*)d_in[15];
    p.bhh_w = (const float*)d_in[16];
    p.hr0 = hr0; p.cr0 = cr0; p.hw0 = hw0; p.cw0 = cw0; p.M0 = M0;
    p.mbuf = mbuf; p.comppre = comppre;
    p.mpart = mpart; p.mxpart = mxpart; p.sumpart = sumpart;
    p.hrb0 = hrB0; p.hrb1 = hrS1; p.crS = crS;
    p.hwb0 = hwB0; p.hwb1 = hwS1; p.cwS = cwS;
    p.outputs = outputs; p.Mw = Mw;
    p.slots = slots;

    k_persist<<<NBLK, 512, 0, stream>>>(p);
}